// Round 5
// baseline (297.595 us; speedup 1.0000x reference)
//
#include <hip/hip_runtime.h>
#include <hip/hip_bf16.h>
#include <stdint.h>

typedef unsigned short u16;
typedef short short8 __attribute__((ext_vector_type(8)));
typedef float floatx4 __attribute__((ext_vector_type(4)));

#define S_LEN 2048
#define NB 2
#define NH 8
#define R_TOK (NB * S_LEN)  // 4096

#define L2_THETA 13.287712379549449f
// attention scale folded into Q, log2 domain: (1/sqrt(128)) * log2(e)
#define QSCALE (0.08838834764831845f * 1.4426950408889634f)

__device__ inline u16 f2bf(float f) {
  union { float f; uint32_t u; } x; x.f = f;
  uint32_t r = (x.u + 0x7fffu + ((x.u >> 16) & 1u)) >> 16;
  return (u16)r;
}
__device__ inline float bf2f(u16 h) {
  union { uint32_t u; float f; } x; x.u = ((uint32_t)h) << 16;
  return x.f;
}
__device__ inline floatx4 mfma16(short8 a, short8 b, floatx4 c) {
  return __builtin_amdgcn_mfma_f32_16x16x32_bf16(a, b, c, 0, 0, 0);
}
__device__ inline uint32_t pkbf(float a, float b) {
  union { __hip_bfloat162 h; uint32_t u; } c;
  c.h = __float22bfloat162_rn(make_float2(a, b));
  return c.u;
}
__device__ __forceinline__ void cp16(const void* g, const void* l) {
  __builtin_amdgcn_global_load_lds(
      (const __attribute__((address_space(1))) uint32_t*)(uintptr_t)g,
      (__attribute__((address_space(3))) uint32_t*)(uintptr_t)l, 16, 0, 0);
}

// ---------------- fused prep: x->bf16, weight transposes, bias concat ----------------
__global__ __launch_bounds__(256) void k_prep(
    const float* __restrict__ x, u16* __restrict__ xbf,
    const float* __restrict__ wdq, const float* __restrict__ wdkv, u16* __restrict__ waT,
    const float* __restrict__ wuq, u16* __restrict__ wQT,
    const float* __restrict__ wukv, u16* __restrict__ wKVT,
    const float* __restrict__ wo, u16* __restrict__ wOT,
    const float* __restrict__ bdq, const float* __restrict__ bdkv,
    float* __restrict__ biasA) {
  __shared__ u16 tile[32][33];
  const int s = blockIdx.x, tid = threadIdx.x;
  const int tx = tid & 31, ty = tid >> 5;
  if (s < 4096) {
    int i = s * 256 + tid;
    float4 v = ((const float4*)x)[i];
    ushort4 o;
    o.x = f2bf(v.x); o.y = f2bf(v.y); o.z = f2bf(v.z); o.w = f2bf(v.w);
    ((ushort4*)xbf)[i] = o;
  } else if (s < 4416) {  // waT: logical [1024][320] -> [320][1024]
    int t = s - 4096, bx = t % 10, by = t / 10;
    int c0 = bx * 32, r0 = by * 32;
#pragma unroll
    for (int i = 0; i < 4; ++i) {
      int r = r0 + ty + i * 8, c = c0 + tx;
      float v = (c < 128) ? wdq[(size_t)r * 128 + c] : wdkv[(size_t)r * 192 + (c - 128)];
      tile[ty + i * 8][tx] = f2bf(v);
    }
    __syncthreads();
#pragma unroll
    for (int i = 0; i < 4; ++i)
      waT[(size_t)(c0 + ty + i * 8) * 1024 + r0 + tx] = tile[tx][ty + i * 8];
  } else {
    const float* in; u16* out; int R, C, bx, by;
    if (s < 4544) { int t = s - 4416; in = wuq; out = wQT; R = 128; C = 1024; bx = t & 31; by = t >> 5; }
    else if (s < 4864) { int t = s - 4544; in = wukv; out = wKVT; R = 128; C = 2560; bx = t % 80; by = t / 80; }
    else if (s < 6912) { int t = s - 4864; in = wo; out = wOT; R = 2048; C = 1024; bx = t & 31; by = t >> 5; }
    else {
      if (tid < 320) biasA[tid] = (tid < 128) ? bdq[tid] : bdkv[tid - 128];
      return;
    }
    int c0 = bx * 32, r0 = by * 32;
#pragma unroll
    for (int i = 0; i < 4; ++i)
      tile[ty + i * 8][tx] = f2bf(in[(size_t)(r0 + ty + i * 8) * C + c0 + tx]);
    __syncthreads();
#pragma unroll
    for (int i = 0; i < 4; ++i)
      out[(size_t)(c0 + ty + i * 8) * R + r0 + tx] = tile[tx][ty + i * 8];
  }
}

// ---------------- 128x128-tile GEMM, B transposed [N][K], double-buffered async ----------
template <int OUT_BF>
__global__ __launch_bounds__(256) void k_gemm_bt(const u16* __restrict__ A,
                                                 const u16* __restrict__ BT,
                                                 const float* __restrict__ bias,
                                                 void* __restrict__ Cout,
                                                 int M, int N, int K) {
  __shared__ __align__(16) u16 Alds[2][128 * 32];
  __shared__ __align__(16) u16 Blds[2][128 * 32];
  const int tid = threadIdx.x;
  const int wave = tid >> 6, lane = tid & 63;
  const int lane15 = lane & 15, quad = lane >> 4;
  const int m0 = blockIdx.y * 128, n0 = blockIdx.x * 128;
  const int mw = (wave & 1) * 64, nw = (wave >> 1) * 64;

  floatx4 acc[4][4];
#pragma unroll
  for (int a = 0; a < 4; ++a)
#pragma unroll
    for (int b = 0; b < 4; ++b) acc[a][b] = (floatx4){0.f, 0.f, 0.f, 0.f};

  const int srow = wave * 32 + (lane >> 2);
  const int scol = (lane & 3) * 8;

  auto stage = [&](int k0, int buf) {
    const u16* ga = A + (size_t)(m0 + srow) * K + k0 + scol;
    cp16(ga, Alds[buf] + srow * 32 + scol);
    cp16(ga + (size_t)16 * K, Alds[buf] + (srow + 16) * 32 + scol);
    const u16* gb = BT + (size_t)(n0 + srow) * K + k0 + scol;
    cp16(gb, Blds[buf] + srow * 32 + scol);
    cp16(gb + (size_t)16 * K, Blds[buf] + (srow + 16) * 32 + scol);
  };

  stage(0, 0);
  int cur = 0;
  for (int k0 = 0; k0 < K; k0 += 32) {
    __syncthreads();
    if (k0 + 32 < K) stage(k0 + 32, cur ^ 1);
    short8 af[4], bf[4];
#pragma unroll
    for (int im = 0; im < 4; ++im)
      af[im] = *(const short8*)&Alds[cur][(mw + im * 16 + lane15) * 32 + quad * 8];
#pragma unroll
    for (int in = 0; in < 4; ++in)
      bf[in] = *(const short8*)&Blds[cur][(nw + in * 16 + lane15) * 32 + quad * 8];
#pragma unroll
    for (int im = 0; im < 4; ++im)
#pragma unroll
      for (int in = 0; in < 4; ++in) acc[im][in] = mfma16(af[im], bf[in], acc[im][in]);
    cur ^= 1;
  }

#pragma unroll
  for (int im = 0; im < 4; ++im)
#pragma unroll
    for (int in = 0; in < 4; ++in)
#pragma unroll
      for (int r = 0; r < 4; ++r) {
        int row = m0 + mw + im * 16 + quad * 4 + r;
        int col = n0 + nw + in * 16 + lane15;
        if (col < N) {
          float v = acc[im][in][r] + bias[col];
          if (OUT_BF)
            ((u16*)Cout)[(size_t)row * N + col] = f2bf(v);
          else
            ((float*)Cout)[(size_t)row * N + col] = v;
        }
      }
}

// ---------------- stage-A epilogue: rmsnorm(cq), rmsnorm(ckv), rope(k_rope) ----------------
__global__ void k_stagea(const float* __restrict__ t0, const float* __restrict__ qnw,
                         const float* __restrict__ kvnw, const int* __restrict__ pos_ids,
                         u16* __restrict__ cq, u16* __restrict__ ckv,
                         u16* __restrict__ krope) {
  int r = blockIdx.x, tid = threadIdx.x;  // 128 threads
  const float* row = t0 + (size_t)r * 320;
  float a = row[tid];
  float b = row[128 + tid];
  float sa = a * a, sb = b * b;
#pragma unroll
  for (int d = 1; d < 64; d <<= 1) {
    sa += __shfl_xor(sa, d);
    sb += __shfl_xor(sb, d);
  }
  __shared__ float red[4];
  if ((tid & 63) == 0) { red[(tid >> 6) * 2] = sa; red[(tid >> 6) * 2 + 1] = sb; }
  __syncthreads();
  sa = red[0] + red[2];
  sb = red[1] + red[3];
  float ra = rsqrtf(sa * (1.0f / 128.0f) + 1e-8f);
  float rb = rsqrtf(sb * (1.0f / 128.0f) + 1e-8f);
  cq[(size_t)r * 128 + tid] = f2bf(qnw[tid] * a * ra);
  ckv[(size_t)r * 128 + tid] = f2bf(kvnw[tid] * b * rb);
  if (tid < 32) {
    float xe = row[256 + 2 * tid], xo = row[256 + 2 * tid + 1];
    float p = (float)pos_ids[r];
    float freq = exp2f(-(2.0f * tid / 64.0f) * L2_THETA);
    float ang = p * freq;
    float c = cosf(ang), s = sinf(ang);
    krope[(size_t)r * 64 + 2 * tid] = f2bf(xe * c - xo * s);
    krope[(size_t)r * 64 + 2 * tid + 1] = f2bf(xe * s + xo * c);
  }
}

// ---------------- stage-B epilogue: rope(q_rope) + scale + scatter ----------------
__global__ void k_stageb(const u16* __restrict__ q, const int* __restrict__ pos_ids,
                         u16* __restrict__ qstates) {
  int r = blockIdx.x, tid = threadIdx.x;  // 256 threads
  int b = r >> 11, s = r & (S_LEN - 1);
  float p = (float)pos_ids[r];
#pragma unroll
  for (int i = 0; i < 4; ++i) {
    int idx = tid + i * 256;
    int h = idx >> 7, d = idx & 127;
    float val;
    if (d < 96) {
      val = bf2f(q[(size_t)r * 1024 + h * 96 + d]);
    } else {
      int j = d - 96, pr = j >> 1;
      float xe = bf2f(q[(size_t)r * 1024 + 768 + h * 32 + 2 * pr]);
      float xo = bf2f(q[(size_t)r * 1024 + 768 + h * 32 + 2 * pr + 1]);
      float freq = exp2f(-(2.0f * pr / 32.0f) * L2_THETA);
      float ang = p * freq;
      float c = cosf(ang), sn = sinf(ang);
      val = (j & 1) ? (xe * sn + xo * c) : (xe * c - xo * sn);
    }
    qstates[((size_t)(b * NH + h) * S_LEN + s) * 128 + d] = f2bf(val * QSCALE);
  }
}

// ---------------- V transpose with the 16x16 PV k-permutation baked in ----------------
// vT[pair][n=256][p=2048]: within each 64-wide k-chunk, p = u*8 + i (u=unit, i=hw):
//   source k-offset = 32*(u>>2) + 16*(i>>2) + 4*(u&3) + (i&3)
// For a ushort4 store at p=a*4 (a in [0,16)): k_base = 32*(a>>3) + 16*(a&1) + 4*((a>>1)&3),
// elements are 4 consecutive source rows.
__global__ __launch_bounds__(256) void k_vt(const u16* __restrict__ kvb, u16* __restrict__ vT) {
  __shared__ u16 tile[64][40];
  const int nx = blockIdx.x;   // 0..7  (32-wide n tile)
  const int sy = blockIdx.y;   // 0..31 (64-wide s tile)
  const int pz = blockIdx.z;   // pair
  const int b = pz >> 3, h = pz & 7;
  const int tid = threadIdx.x;
  const int n0 = nx * 32, s0 = sy * 64;
  {
    int rr = tid >> 2, cc = (tid & 3) * 8;
    const u16* src = kvb + ((size_t)(b * S_LEN + s0 + rr)) * 2560 + 512 + h * 256 + n0 + cc;
    *(short8*)&tile[rr][cc] = *(const short8*)src;
  }
  __syncthreads();
#pragma unroll
  for (int j = 0; j < 2; ++j) {
    int e = tid * 2 + j;
    int n = e >> 4, a = e & 15;
    int sb = 32 * (a >> 3) + 16 * (a & 1) + 4 * ((a >> 1) & 3);
    ushort4 o;
    o.x = tile[sb][n]; o.y = tile[sb + 1][n]; o.z = tile[sb + 2][n]; o.w = tile[sb + 3][n];
    *(ushort4*)&vT[((size_t)(pz * 256 + n0 + n)) * 2048 + s0 + a * 4] = o;
  }
}

// ---------------- flash attention: n-split waves, 2-phase double-buffered (r5) ----------
// (r4 resubmit: container infra failure, kernel never ran.)
// r3 post-mortem: kernel is LDS-READ-BANDWIDTH bound (384 KB/chunk/CU = ~4.6k cyc at
// 85 B/cyc >> any other pipe). Fix: each wave owns 32 q-rows x 128 n-cols.
// 8 waves = 4 q-groups (wave&3, 32 rows) x 2 n-halves (wave>>2, 128 cols).
// - V: each wave reads HALF the tile (16 KB), each b-frag feeds 2 MFMAs (2 q-subgroups)
// - K: each kf read feeds 2 MFMAs -> LDS/chunk/CU: 384 -> 256 KB (-33%)
// Cost: QK+softmax duplicated across the n-half pair (exp2 x2 = 512 cyc/SIMD, still far
// under LDS budget; two independent softmax chains add ILP). VGPR ~200 at (512,2) cap.
// Pipeline, staging, K/V LDS layouts identical to r3 (passed, 89.3us).
__global__ __launch_bounds__(512, 2) void k_attn(const u16* __restrict__ qstates,
                                                 const u16* __restrict__ kv,
                                                 const u16* __restrict__ krope,
                                                 const u16* __restrict__ vT,
                                                 u16* __restrict__ attn_out) {
  const int pair = blockIdx.x;  // 0..15 (pair-major: XCD = pair%8)
  const int qblk = blockIdx.y;  // 0..15
  const int b = pair >> 3, h = pair & 7;
  const int tid = threadIdx.x;
  const int wave = tid >> 6, lane = tid & 63;
  const int lane15 = lane & 15, quad = lane >> 4;
  const int qg = wave & 3;   // q-group: 32 rows (also K-staging rowgroup)
  const int nh = wave >> 2;  // n-half: 128 cols (also K-staging unit-half)

  __shared__ __align__(16) u16 Klds[2][64 * 128];   // 2 x 16 KB
  __shared__ __align__(16) u16 Vlds[2][256 * 64];   // 2 x 32 KB

  const int qrow0 = qblk * 128 + qg * 32;
  short8 qfrag[2][4];
#pragma unroll
  for (int s = 0; s < 2; ++s) {
    const u16* qb =
        qstates + ((size_t)(b * NH + h) * S_LEN + qrow0 + s * 16 + lane15) * 128 + quad * 8;
#pragma unroll
    for (int c = 0; c < 4; ++c) qfrag[s][c] = *(const short8*)(qb + c * 32);
  }

  floatx4 o_acc[2][8];
#pragma unroll
  for (int s = 0; s < 2; ++s)
#pragma unroll
    for (int g = 0; g < 8; ++g) o_acc[s][g] = (floatx4){0.f, 0.f, 0.f, 0.f};
  float m_i[2] = {-1e30f, -1e30f};
  float l_i[2] = {0.f, 0.f};  // per-lane PARTIAL row-sums; reduced at epilogue

  // ---- hoisted, ch-invariant LDS read offsets (u16 units) ----
  const int kbase = (quad * 16 + lane15) * 8;  // + (t*16+c*4)*128 (imm)
  // V bases: n = nh*128 + g*16 + lane15. Swizzle sw=(n^(n>>3))&7 depends only on (g&3,
  // lane15); positional term n*64 = nh*8192 + (g>>2)*4096 + ((g&3)*16+lane15)*64.
  int vo0[4], vo1[4];
#pragma unroll
  for (int ph = 0; ph < 4; ++ph) {
    int n = ph * 16 + lane15;
    int sw = (n ^ (n >> 3)) & 7;
    vo0[ph] = nh * 8192 + n * 64 + ((quad ^ sw) & 7) * 8;
    vo1[ph] = nh * 8192 + n * 64 + (((quad | 4) ^ sw) & 7) * 8;
  }

  // K staging (512 thr, 2 cp16/thread): row = qg*16+lane15, unit u = nh*8 + 4j + quad.
  const u16* kp[2];
  int kstr[2];
  int kdst[2];
#pragma unroll
  for (int j = 0; j < 2; ++j) {
    int u = nh * 8 + j * 4 + quad;
    const u16* base;
    int str;
    if (u < 8) { base = kv + h * 64 + u * 8; str = 2560; }
    else { base = krope + (u - 8) * 8; str = 64; }
    kp[j] = base + (size_t)(b * S_LEN + qg * 16 + lane15) * str;
    kstr[j] = str;
    kdst[j] = (qg * 256 + (nh * 2 + j) * 64 + lane) * 8;
  }
  // V staging (512 thr, 4 cp16/thread): n = oi*64 + (tid>>3), slot = tid&7
  const int vn6 = tid >> 3, vsl = tid & 7;
  const u16* vp[4];
#pragma unroll
  for (int oi = 0; oi < 4; ++oi) {
    int n = oi * 64 + vn6;
    int u = vsl ^ ((n ^ (n >> 3)) & 7);
    vp[oi] = vT + ((size_t)pair * 256 + n) * 2048 + u * 8;
  }

  auto issueK = [&](int buf) {
#pragma unroll
    for (int j = 0; j < 2; ++j) {
      cp16(kp[j], &Klds[buf][kdst[j]]);
      kp[j] += (size_t)64 * kstr[j];
    }
  };
  auto issueV = [&](int buf) {
#pragma unroll
    for (int oi = 0; oi < 4; ++oi) {
      cp16(vp[oi], &Vlds[buf][(oi * 512 + tid) * 8]);
      vp[oi] += 64;
    }
  };

  // prologue: fill buf0, drain, converge
  issueK(0);
  issueV(0);
  asm volatile("s_waitcnt vmcnt(0)" ::: "memory");
  __builtin_amdgcn_sched_barrier(0);
  __builtin_amdgcn_s_barrier();

  int cur = 0;
  for (int ch = 0; ch < S_LEN / 64; ++ch) {
    if (ch + 1 < S_LEN / 64) {
      issueK(cur ^ 1);
      issueV(cur ^ 1);
    }

    // S^T = K * Q^T for both q-subgroups; each kf read feeds 2 MFMAs
    floatx4 st[2][4];
#pragma unroll
    for (int s = 0; s < 2; ++s)
#pragma unroll
      for (int t = 0; t < 4; ++t) st[s][t] = (floatx4){0.f, 0.f, 0.f, 0.f};
    __builtin_amdgcn_s_setprio(1);
#pragma unroll
    for (int c = 0; c < 4; ++c) {
#pragma unroll
      for (int t = 0; t < 4; ++t) {
        short8 kf = *(const short8*)&Klds[cur][kbase + (t * 16 + c * 4) * 128];
        st[0][t] = mfma16(kf, qfrag[0][c], st[0][t]);
        st[1][t] = mfma16(kf, qfrag[1][c], st[1][t]);
      }
    }
    __builtin_amdgcn_s_setprio(0);

    // online softmax per q-subgroup (two independent chains -> ILP)
    union { short8 s; uint4 u; } a01[2], a23[2];
#pragma unroll
    for (int s = 0; s < 2; ++s) {
      float mloc = st[s][0][0];
#pragma unroll
      for (int t = 0; t < 4; ++t)
#pragma unroll
        for (int r = 0; r < 4; ++r) mloc = fmaxf(mloc, st[s][t][r]);
      mloc = fmaxf(mloc, __shfl_xor(mloc, 16));
      mloc = fmaxf(mloc, __shfl_xor(mloc, 32));

      // defer-max: only rescale when max grew by >8 (log2 domain); P bounded by 2^8
      const bool resc = __any(mloc > m_i[s] + 8.0f);
      const float mref = resc ? fmaxf(m_i[s], mloc) : m_i[s];

      float rs = 0.f;
      {
        float p0, p1, p2, p3;
        p0 = exp2f(st[s][0][0] - mref); p1 = exp2f(st[s][0][1] - mref);
        p2 = exp2f(st[s][0][2] - mref); p3 = exp2f(st[s][0][3] - mref);
        rs += (p0 + p1) + (p2 + p3);
        a01[s].u.x = pkbf(p0, p1); a01[s].u.y = pkbf(p2, p3);
        p0 = exp2f(st[s][1][0] - mref); p1 = exp2f(st[s][1][1] - mref);
        p2 = exp2f(st[s][1][2] - mref); p3 = exp2f(st[s][1][3] - mref);
        rs += (p0 + p1) + (p2 + p3);
        a01[s].u.z = pkbf(p0, p1); a01[s].u.w = pkbf(p2, p3);
        p0 = exp2f(st[s][2][0] - mref); p1 = exp2f(st[s][2][1] - mref);
        p2 = exp2f(st[s][2][2] - mref); p3 = exp2f(st[s][2][3] - mref);
        rs += (p0 + p1) + (p2 + p3);
        a23[s].u.x = pkbf(p0, p1); a23[s].u.y = pkbf(p2, p3);
        p0 = exp2f(st[s][3][0] - mref); p1 = exp2f(st[s][3][1] - mref);
        p2 = exp2f(st[s][3][2] - mref); p3 = exp2f(st[s][3][3] - mref);
        rs += (p0 + p1) + (p2 + p3);
        a23[s].u.z = pkbf(p0, p1); a23[s].u.w = pkbf(p2, p3);
      }

      if (resc) {  // rare after chunk 0 (THR=8)
        float alpha = exp2f(m_i[s] - mref);
        m_i[s] = mref;
        l_i[s] = l_i[s] * alpha + rs;
        float al[4];
#pragma unroll
        for (int r = 0; r < 4; ++r) al[r] = __shfl(alpha, quad * 4 + r, 16);
#pragma unroll
        for (int g = 0; g < 8; ++g) {
          o_acc[s][g][0] *= al[0]; o_acc[s][g][1] *= al[1];
          o_acc[s][g][2] *= al[2]; o_acc[s][g][3] *= al[3];
        }
      } else {
        l_i[s] += rs;
      }
    }

    // PV: each b-frag (single b128 read) feeds both q-subgroups
    __builtin_amdgcn_s_setprio(1);
#pragma unroll
    for (int g = 0; g < 8; ++g) {
      short8 b01 = *(const short8*)&Vlds[cur][vo0[g & 3] + (g >> 2) * 4096];
      short8 b23 = *(const short8*)&Vlds[cur][vo1[g & 3] + (g >> 2) * 4096];
      o_acc[0][g] = mfma16(a01[0].s, b01, o_acc[0][g]);
      o_acc[1][g] = mfma16(a01[1].s, b01, o_acc[1][g]);
      o_acc[0][g] = mfma16(a23[0].s, b23, o_acc[0][g]);
      o_acc[1][g] = mfma16(a23[1].s, b23, o_acc[1][g]);
    }
    __builtin_amdgcn_s_setprio(0);

    // single per-chunk sync: next-chunk loads had all of compute to land;
    // barrier seals this chunk's LDS reads before buf[cur] is overwritten.
    asm volatile("s_waitcnt vmcnt(0)" ::: "memory");
    __builtin_amdgcn_sched_barrier(0);
    __builtin_amdgcn_s_barrier();
    cur ^= 1;
  }

  // epilogue: reduce per-quad partial row-sums, normalize, store
#pragma unroll
  for (int s = 0; s < 2; ++s) {
    float lsum = l_i[s];
    lsum += __shfl_xor(lsum, 16);
    lsum += __shfl_xor(lsum, 32);
    float rl = 1.0f / lsum;
    float linv[4];
#pragma unroll
    for (int r = 0; r < 4; ++r) linv[r] = __shfl(rl, quad * 4 + r, 16);
#pragma unroll
    for (int g = 0; g < 8; ++g) {
#pragma unroll
      for (int r = 0; r < 4; ++r) {
        int row = qrow0 + s * 16 + quad * 4 + r;
        int col = h * 256 + nh * 128 + g * 16 + lane15;
        attn_out[((size_t)b * S_LEN + row) * 2048 + col] = f2bf(o_acc[s][g][r] * linv[r]);
      }
    }
  }
}

extern "C" void kernel_launch(void* const* d_in, const int* in_sizes, int n_in,
                              void* d_out, int out_size, void* d_ws, size_t ws_size,
                              hipStream_t stream) {
  const float* x = (const float*)d_in[0];
  const int* pos = (const int*)d_in[1];
  const float* wdq = (const float*)d_in[2];
  const float* bdq = (const float*)d_in[3];
  const float* qnw = (const float*)d_in[4];
  const float* wuq = (const float*)d_in[5];
  const float* buq = (const float*)d_in[6];
  const float* wdkv = (const float*)d_in[7];
  const float* bdkv = (const float*)d_in[8];
  const float* kvnw = (const float*)d_in[9];
  const float* wukv = (const float*)d_in[10];
  const float* bukv = (const float*)d_in[11];
  const float* wo = (const float*)d_in[12];
  const float* bo = (const float*)d_in[13];
  float* out = (float*)d_out;

  char* ws = (char*)d_ws;
  size_t off = 0;
  auto alloc = [&](size_t bytes) {
    char* p = ws + off;
    off += (bytes + 255) & ~(size_t)255;
    return p;
  };
  // vT (16.78MB) aliases xbf+t0+qout (22MB): all dead before k_vt runs
  u16* xbf = (u16*)alloc((size_t)R_TOK * 1024 * 2);    // dead after gemm A
  float* t0 = (float*)alloc((size_t)R_TOK * 320 * 4);  // dead after stagea
  u16* qout = (u16*)alloc((size_t)R_TOK * 1024 * 2);   // dead after stageb
  u16* vT = (u16*)d_ws;                                // alias of the three above
  u16* waT = (u16*)alloc((size_t)384 * 1024 * 2);      // padded 320->384 rows
  float* biasA = (float*)alloc(320 * 4);
  u16* wQT = (u16*)alloc((size_t)1024 * 128 * 2);
  u16* wKVT = (u16*)alloc((size_t)2560 * 128 * 2);
  u16* wOT = (u16*)alloc((size_t)1024 * 2048 * 2);
  u16* cq = (u16*)alloc((size_t)R_TOK * 128 * 2);
  u16* ckv = (u16*)alloc((size_t)R_TOK * 128 * 2);
  u16* krope = (u16*)alloc((size_t)R_TOK * 64 * 2);
  u16* qst = (u16*)alloc((size_t)R_TOK * 1024 * 2);
  u16* kvb = (u16*)alloc((size_t)R_TOK * 2560 * 2);
  u16* attnb = (u16*)alloc((size_t)R_TOK * 2048 * 2);
  (void)ws_size; (void)n_in; (void)in_sizes; (void)out_size;

  k_prep<<<6913, 256, 0, stream>>>(x, xbf, wdq, wdkv, waT, wuq, wQT, wukv, wKVT, wo, wOT,
                                   bdq, bdkv, biasA);

  // stage A: x @ [w_dq | w_dkv_kr] -> t0 fp32
  k_gemm_bt<0><<<dim3(3, 32), 256, 0, stream>>>(xbf, waT, biasA, t0, R_TOK, 320, 1024);
  k_stagea<<<R_TOK, 128, 0, stream>>>(t0, qnw, kvnw, pos, cq, ckv, krope);
  // stage B: q up-proj, rope+scale+scatter
  k_gemm_bt<1><<<dim3(8, 32), 256, 0, stream>>>(cq, wQT, buq, qout, R_TOK, 1024, 128);
  k_stageb<<<R_TOK, 256, 0, stream>>>(qout, pos, qst);
  // kv up-proj
  k_gemm_bt<1><<<dim3(20, 32), 256, 0, stream>>>(ckv, wKVT, bukv, kvb, R_TOK, 2560, 128);
  // V transpose (16x16 permuted-k layout); xbf/t0/qout dead here
  k_vt<<<dim3(8, 32, 16), 256, 0, stream>>>(kvb, vT);
  // attention: 256 blocks (1/CU, 96KB LDS, 8 waves = 2/SIMD), 512 threads
  // waves = 4 q-groups x 2 n-halves; 128 q-rows x 256 n per block
  k_attn<<<dim3(16, 16), 512, 0, stream>>>(qst, kvb, krope, vT, attnb);
  // output projection -> fp32 out
  k_gemm_bt<0><<<dim3(8, 32), 256, 0, stream>>>(attnb, wOT, bo, out, R_TOK, 1024, 2048);
}

// Round 6
// 284.326 us; speedup vs baseline: 1.0467x; 1.0467x over previous
//
#include <hip/hip_runtime.h>
#include <hip/hip_bf16.h>
#include <stdint.h>

typedef unsigned short u16;
typedef short short8 __attribute__((ext_vector_type(8)));
typedef float floatx4 __attribute__((ext_vector_type(4)));

#define S_LEN 2048
#define NB 2
#define NH 8
#define R_TOK (NB * S_LEN)  // 4096

#define L2_THETA 13.287712379549449f
// attention scale folded into Q, log2 domain: (1/sqrt(128)) * log2(e)
#define QSCALE (0.08838834764831845f * 1.4426950408889634f)

__device__ inline u16 f2bf(float f) {
  union { float f; uint32_t u; } x; x.f = f;
  uint32_t r = (x.u + 0x7fffu + ((x.u >> 16) & 1u)) >> 16;
  return (u16)r;
}
__device__ inline float bf2f(u16 h) {
  union { uint32_t u; float f; } x; x.u = ((uint32_t)h) << 16;
  return x.f;
}
__device__ inline floatx4 mfma16(short8 a, short8 b, floatx4 c) {
  return __builtin_amdgcn_mfma_f32_16x16x32_bf16(a, b, c, 0, 0, 0);
}
__device__ inline uint32_t pkbf(float a, float b) {
  union { __hip_bfloat162 h; uint32_t u; } c;
  c.h = __float22bfloat162_rn(make_float2(a, b));
  return c.u;
}
__device__ __forceinline__ void cp16(const void* g, const void* l) {
  __builtin_amdgcn_global_load_lds(
      (const __attribute__((address_space(1))) uint32_t*)(uintptr_t)g,
      (__attribute__((address_space(3))) uint32_t*)(uintptr_t)l, 16, 0, 0);
}

// ---------------- fused prep: x->bf16, weight transposes, bias concat ----------------
__global__ __launch_bounds__(256) void k_prep(
    const float* __restrict__ x, u16* __restrict__ xbf,
    const float* __restrict__ wdq, const float* __restrict__ wdkv, u16* __restrict__ waT,
    const float* __restrict__ wuq, u16* __restrict__ wQT,
    const float* __restrict__ wukv, u16* __restrict__ wKVT,
    const float* __restrict__ wo, u16* __restrict__ wOT,
    const float* __restrict__ bdq, const float* __restrict__ bdkv,
    float* __restrict__ biasA) {
  __shared__ u16 tile[32][33];
  const int s = blockIdx.x, tid = threadIdx.x;
  const int tx = tid & 31, ty = tid >> 5;
  if (s < 4096) {
    int i = s * 256 + tid;
    float4 v = ((const float4*)x)[i];
    ushort4 o;
    o.x = f2bf(v.x); o.y = f2bf(v.y); o.z = f2bf(v.z); o.w = f2bf(v.w);
    ((ushort4*)xbf)[i] = o;
  } else if (s < 4416) {  // waT: logical [1024][320] -> [320][1024]
    int t = s - 4096, bx = t % 10, by = t / 10;
    int c0 = bx * 32, r0 = by * 32;
#pragma unroll
    for (int i = 0; i < 4; ++i) {
      int r = r0 + ty + i * 8, c = c0 + tx;
      float v = (c < 128) ? wdq[(size_t)r * 128 + c] : wdkv[(size_t)r * 192 + (c - 128)];
      tile[ty + i * 8][tx] = f2bf(v);
    }
    __syncthreads();
#pragma unroll
    for (int i = 0; i < 4; ++i)
      waT[(size_t)(c0 + ty + i * 8) * 1024 + r0 + tx] = tile[tx][ty + i * 8];
  } else {
    const float* in; u16* out; int R, C, bx, by;
    if (s < 4544) { int t = s - 4416; in = wuq; out = wQT; R = 128; C = 1024; bx = t & 31; by = t >> 5; }
    else if (s < 4864) { int t = s - 4544; in = wukv; out = wKVT; R = 128; C = 2560; bx = t % 80; by = t / 80; }
    else if (s < 6912) { int t = s - 4864; in = wo; out = wOT; R = 2048; C = 1024; bx = t & 31; by = t >> 5; }
    else {
      if (tid < 320) biasA[tid] = (tid < 128) ? bdq[tid] : bdkv[tid - 128];
      return;
    }
    int c0 = bx * 32, r0 = by * 32;
#pragma unroll
    for (int i = 0; i < 4; ++i)
      tile[ty + i * 8][tx] = f2bf(in[(size_t)(r0 + ty + i * 8) * C + c0 + tx]);
    __syncthreads();
#pragma unroll
    for (int i = 0; i < 4; ++i)
      out[(size_t)(c0 + ty + i * 8) * R + r0 + tx] = tile[tx][ty + i * 8];
  }
}

// ---------------- 128x128-tile GEMM, B transposed [N][K], double-buffered async ----------
template <int OUT_BF>
__global__ __launch_bounds__(256) void k_gemm_bt(const u16* __restrict__ A,
                                                 const u16* __restrict__ BT,
                                                 const float* __restrict__ bias,
                                                 void* __restrict__ Cout,
                                                 int M, int N, int K) {
  __shared__ __align__(16) u16 Alds[2][128 * 32];
  __shared__ __align__(16) u16 Blds[2][128 * 32];
  const int tid = threadIdx.x;
  const int wave = tid >> 6, lane = tid & 63;
  const int lane15 = lane & 15, quad = lane >> 4;
  const int m0 = blockIdx.y * 128, n0 = blockIdx.x * 128;
  const int mw = (wave & 1) * 64, nw = (wave >> 1) * 64;

  floatx4 acc[4][4];
#pragma unroll
  for (int a = 0; a < 4; ++a)
#pragma unroll
    for (int b = 0; b < 4; ++b) acc[a][b] = (floatx4){0.f, 0.f, 0.f, 0.f};

  const int srow = wave * 32 + (lane >> 2);
  const int scol = (lane & 3) * 8;

  auto stage = [&](int k0, int buf) {
    const u16* ga = A + (size_t)(m0 + srow) * K + k0 + scol;
    cp16(ga, Alds[buf] + srow * 32 + scol);
    cp16(ga + (size_t)16 * K, Alds[buf] + (srow + 16) * 32 + scol);
    const u16* gb = BT + (size_t)(n0 + srow) * K + k0 + scol;
    cp16(gb, Blds[buf] + srow * 32 + scol);
    cp16(gb + (size_t)16 * K, Blds[buf] + (srow + 16) * 32 + scol);
  };

  stage(0, 0);
  int cur = 0;
  for (int k0 = 0; k0 < K; k0 += 32) {
    __syncthreads();
    if (k0 + 32 < K) stage(k0 + 32, cur ^ 1);
    short8 af[4], bf[4];
#pragma unroll
    for (int im = 0; im < 4; ++im)
      af[im] = *(const short8*)&Alds[cur][(mw + im * 16 + lane15) * 32 + quad * 8];
#pragma unroll
    for (int in = 0; in < 4; ++in)
      bf[in] = *(const short8*)&Blds[cur][(nw + in * 16 + lane15) * 32 + quad * 8];
#pragma unroll
    for (int im = 0; im < 4; ++im)
#pragma unroll
      for (int in = 0; in < 4; ++in) acc[im][in] = mfma16(af[im], bf[in], acc[im][in]);
    cur ^= 1;
  }

#pragma unroll
  for (int im = 0; im < 4; ++im)
#pragma unroll
    for (int in = 0; in < 4; ++in)
#pragma unroll
      for (int r = 0; r < 4; ++r) {
        int row = m0 + mw + im * 16 + quad * 4 + r;
        int col = n0 + nw + in * 16 + lane15;
        if (col < N) {
          float v = acc[im][in][r] + bias[col];
          if (OUT_BF)
            ((u16*)Cout)[(size_t)row * N + col] = f2bf(v);
          else
            ((float*)Cout)[(size_t)row * N + col] = v;
        }
      }
}

// ------- fused Q GEMM (cq @ wQT + buq) + rope + scale + scatter to qstates (r6) -------
// M=4096, N=1024, K=128. Mainloop identical to k_gemm_bt. Epilogue replaces k_stageb:
// saves the 16MB qout round-trip + one launch. Rope pairs (col, col^1) are adjacent
// lanes (lane15^1) -> one __shfl_xor; nope/rope split is block-uniform (n0 >= 768).
__global__ __launch_bounds__(256) void k_gemm_q(const u16* __restrict__ A,
                                                const u16* __restrict__ BT,
                                                const float* __restrict__ bias,
                                                const int* __restrict__ pos_ids,
                                                u16* __restrict__ qstates) {
  const int K = 128;
  __shared__ __align__(16) u16 Alds[2][128 * 32];
  __shared__ __align__(16) u16 Blds[2][128 * 32];
  const int tid = threadIdx.x;
  const int wave = tid >> 6, lane = tid & 63;
  const int lane15 = lane & 15, quad = lane >> 4;
  const int m0 = blockIdx.y * 128, n0 = blockIdx.x * 128;
  const int mw = (wave & 1) * 64, nw = (wave >> 1) * 64;

  floatx4 acc[4][4];
#pragma unroll
  for (int a = 0; a < 4; ++a)
#pragma unroll
    for (int b = 0; b < 4; ++b) acc[a][b] = (floatx4){0.f, 0.f, 0.f, 0.f};

  const int srow = wave * 32 + (lane >> 2);
  const int scol = (lane & 3) * 8;
  auto stage = [&](int k0, int buf) {
    const u16* ga = A + (size_t)(m0 + srow) * K + k0 + scol;
    cp16(ga, Alds[buf] + srow * 32 + scol);
    cp16(ga + (size_t)16 * K, Alds[buf] + (srow + 16) * 32 + scol);
    const u16* gb = BT + (size_t)(n0 + srow) * K + k0 + scol;
    cp16(gb, Blds[buf] + srow * 32 + scol);
    cp16(gb + (size_t)16 * K, Blds[buf] + (srow + 16) * 32 + scol);
  };

  stage(0, 0);
  int cur = 0;
  for (int k0 = 0; k0 < K; k0 += 32) {
    __syncthreads();
    if (k0 + 32 < K) stage(k0 + 32, cur ^ 1);
    short8 af[4], bf[4];
#pragma unroll
    for (int im = 0; im < 4; ++im)
      af[im] = *(const short8*)&Alds[cur][(mw + im * 16 + lane15) * 32 + quad * 8];
#pragma unroll
    for (int in = 0; in < 4; ++in)
      bf[in] = *(const short8*)&Blds[cur][(nw + in * 16 + lane15) * 32 + quad * 8];
#pragma unroll
    for (int im = 0; im < 4; ++im)
#pragma unroll
      for (int in = 0; in < 4; ++in) acc[im][in] = mfma16(af[im], bf[in], acc[im][in]);
    cur ^= 1;
  }

  const bool ropeblk = (n0 >= 768);  // block-uniform: bx>=6
#pragma unroll
  for (int in = 0; in < 4; ++in) {
    const int col = n0 + nw + in * 16 + lane15;
#pragma unroll
    for (int im = 0; im < 4; ++im) {
      if (!ropeblk) {
        const int h = col / 96, d = col - h * 96;
#pragma unroll
        for (int r = 0; r < 4; ++r) {
          int row = m0 + mw + im * 16 + quad * 4 + r;
          int b = row >> 11, s = row & (S_LEN - 1);
          float v = acc[im][in][r] + bias[col];
          qstates[((size_t)(b * NH + h) * S_LEN + s) * 128 + d] = f2bf(v * QSCALE);
        }
      } else {
        const int j = (col - 768) & 31, h = (col - 768) >> 5, pr = j >> 1;
        const float freq = exp2f(-(2.0f * pr / 32.0f) * L2_THETA);
#pragma unroll
        for (int r = 0; r < 4; ++r) {
          int row = m0 + mw + im * 16 + quad * 4 + r;
          int b = row >> 11, s = row & (S_LEN - 1);
          float v = acc[im][in][r] + bias[col];
          float vp = __shfl_xor(v, 1);  // partner col^1 = lane15^1, same row
          float xe = (lane & 1) ? vp : v;
          float xo = (lane & 1) ? v : vp;
          float p = (float)pos_ids[row];
          float ang = p * freq;
          float c = cosf(ang), sn = sinf(ang);
          float val = (j & 1) ? (xe * sn + xo * c) : (xe * c - xo * sn);
          qstates[((size_t)(b * NH + h) * S_LEN + s) * 128 + 96 + j] = f2bf(val * QSCALE);
        }
      }
    }
  }
}

// ------- fused KV GEMM (ckv @ wKVT + bukv) with k_vt folded into the epilogue (r6) -------
// M=4096, N=2560, K=128. cols<512 (k_nope): normal kvb write (stride 2560; V region of
// kvb is never written nor read). cols>=512 (V): acc[im][in][0..3] = 4 consecutive s-rows
// for a fixed col = exactly one k_vt ushort4. Inverse k-permutation: bb=(srow&63)>>2 with
// bits b3b2b1b0 -> a = 8*b3+4*b1+2*b0+b2, p = (srow&~63) + a*4 (spot-verified at
// srow=0,4,8,16,32). Saves k_vt's 33.5MB round-trip + kvb's 16MB V-write + one launch.
__global__ __launch_bounds__(256) void k_gemm_kv(const u16* __restrict__ A,
                                                 const u16* __restrict__ BT,
                                                 const float* __restrict__ bias,
                                                 u16* __restrict__ kvb,
                                                 u16* __restrict__ vT) {
  const int K = 128, N = 2560;
  __shared__ __align__(16) u16 Alds[2][128 * 32];
  __shared__ __align__(16) u16 Blds[2][128 * 32];
  const int tid = threadIdx.x;
  const int wave = tid >> 6, lane = tid & 63;
  const int lane15 = lane & 15, quad = lane >> 4;
  const int m0 = blockIdx.y * 128, n0 = blockIdx.x * 128;
  const int mw = (wave & 1) * 64, nw = (wave >> 1) * 64;

  floatx4 acc[4][4];
#pragma unroll
  for (int a = 0; a < 4; ++a)
#pragma unroll
    for (int b = 0; b < 4; ++b) acc[a][b] = (floatx4){0.f, 0.f, 0.f, 0.f};

  const int srow = wave * 32 + (lane >> 2);
  const int scol = (lane & 3) * 8;
  auto stage = [&](int k0, int buf) {
    const u16* ga = A + (size_t)(m0 + srow) * K + k0 + scol;
    cp16(ga, Alds[buf] + srow * 32 + scol);
    cp16(ga + (size_t)16 * K, Alds[buf] + (srow + 16) * 32 + scol);
    const u16* gb = BT + (size_t)(n0 + srow) * K + k0 + scol;
    cp16(gb, Blds[buf] + srow * 32 + scol);
    cp16(gb + (size_t)16 * K, Blds[buf] + (srow + 16) * 32 + scol);
  };

  stage(0, 0);
  int cur = 0;
  for (int k0 = 0; k0 < K; k0 += 32) {
    __syncthreads();
    if (k0 + 32 < K) stage(k0 + 32, cur ^ 1);
    short8 af[4], bf[4];
#pragma unroll
    for (int im = 0; im < 4; ++im)
      af[im] = *(const short8*)&Alds[cur][(mw + im * 16 + lane15) * 32 + quad * 8];
#pragma unroll
    for (int in = 0; in < 4; ++in)
      bf[in] = *(const short8*)&Blds[cur][(nw + in * 16 + lane15) * 32 + quad * 8];
#pragma unroll
    for (int im = 0; im < 4; ++im)
#pragma unroll
      for (int in = 0; in < 4; ++in) acc[im][in] = mfma16(af[im], bf[in], acc[im][in]);
    cur ^= 1;
  }

  if (n0 < 512) {  // k_nope region: block-uniform (bx<4)
#pragma unroll
    for (int im = 0; im < 4; ++im)
#pragma unroll
      for (int in = 0; in < 4; ++in)
#pragma unroll
        for (int r = 0; r < 4; ++r) {
          int row = m0 + mw + im * 16 + quad * 4 + r;
          int col = n0 + nw + in * 16 + lane15;
          kvb[(size_t)row * N + col] = f2bf(acc[im][in][r] + bias[col]);
        }
  } else {  // V region -> vT (permuted-k layout), one ushort4 per (im,in)
#pragma unroll
    for (int im = 0; im < 4; ++im) {
      const int row0 = m0 + mw + im * 16 + quad * 4;
      const int b = row0 >> 11, srow0 = row0 & (S_LEN - 1);
      const int sc = srow0 & ~63, bb = (srow0 & 63) >> 2;
      const int a = (bb & 8) | (((bb >> 1) & 1) << 2) | ((bb & 1) << 1) | ((bb >> 2) & 1);
#pragma unroll
      for (int in = 0; in < 4; ++in) {
        const int col = n0 + nw + in * 16 + lane15;
        const int c2 = col - 512;
        const int hv = c2 >> 8, n = c2 & 255;
        const float bv = bias[col];
        ushort4 o;
        o.x = f2bf(acc[im][in][0] + bv);
        o.y = f2bf(acc[im][in][1] + bv);
        o.z = f2bf(acc[im][in][2] + bv);
        o.w = f2bf(acc[im][in][3] + bv);
        *(ushort4*)&vT[((size_t)((b * NH + hv) * 256 + n)) * 2048 + sc + a * 4] = o;
      }
    }
  }
}

// ---------------- stage-A epilogue: rmsnorm(cq), rmsnorm(ckv), rope(k_rope) ----------------
__global__ void k_stagea(const float* __restrict__ t0, const float* __restrict__ qnw,
                         const float* __restrict__ kvnw, const int* __restrict__ pos_ids,
                         u16* __restrict__ cq, u16* __restrict__ ckv,
                         u16* __restrict__ krope) {
  int r = blockIdx.x, tid = threadIdx.x;  // 128 threads
  const float* row = t0 + (size_t)r * 320;
  float a = row[tid];
  float b = row[128 + tid];
  float sa = a * a, sb = b * b;
#pragma unroll
  for (int d = 1; d < 64; d <<= 1) {
    sa += __shfl_xor(sa, d);
    sb += __shfl_xor(sb, d);
  }
  __shared__ float red[4];
  if ((tid & 63) == 0) { red[(tid >> 6) * 2] = sa; red[(tid >> 6) * 2 + 1] = sb; }
  __syncthreads();
  sa = red[0] + red[2];
  sb = red[1] + red[3];
  float ra = rsqrtf(sa * (1.0f / 128.0f) + 1e-8f);
  float rb = rsqrtf(sb * (1.0f / 128.0f) + 1e-8f);
  cq[(size_t)r * 128 + tid] = f2bf(qnw[tid] * a * ra);
  ckv[(size_t)r * 128 + tid] = f2bf(kvnw[tid] * b * rb);
  if (tid < 32) {
    float xe = row[256 + 2 * tid], xo = row[256 + 2 * tid + 1];
    float p = (float)pos_ids[r];
    float freq = exp2f(-(2.0f * tid / 64.0f) * L2_THETA);
    float ang = p * freq;
    float c = cosf(ang), s = sinf(ang);
    krope[(size_t)r * 64 + 2 * tid] = f2bf(xe * c - xo * s);
    krope[(size_t)r * 64 + 2 * tid + 1] = f2bf(xe * s + xo * c);
  }
}

// ---------------- flash attention: 2-phase double-buffered pipeline (r3-exact) ----------
// r5 post-mortem: reverted to this version (89.3us, passed). The n-split variant (r5)
// halved LDS V-reads+conflicts but duplicated QK MFMA (+33%) and softmax VALU (x2) ->
// +26% time. This structure is ~90% LDS-pipe-busy (reads+conflicts+staging-writes) and
// empirically the best of r2/r3/r5.
__global__ __launch_bounds__(512) void k_attn(const u16* __restrict__ qstates,
                                              const u16* __restrict__ kv,
                                              const u16* __restrict__ krope,
                                              const u16* __restrict__ vT,
                                              u16* __restrict__ attn_out) {
  const int pair = blockIdx.x;  // 0..15 (pair-major: XCD = pair%8)
  const int qblk = blockIdx.y;  // 0..15
  const int b = pair >> 3, h = pair & 7;
  const int tid = threadIdx.x;
  const int wave = tid >> 6, lane = tid & 63;
  const int lane15 = lane & 15, quad = lane >> 4;
  const int w4 = wave & 3, half = wave >> 2;

  __shared__ __align__(16) u16 Klds[2][64 * 128];   // 2 x 16 KB
  __shared__ __align__(16) u16 Vlds[2][256 * 64];   // 2 x 32 KB

  const int qrow0 = qblk * 128 + wave * 16;
  short8 qfrag[4];
  {
    const u16* qb = qstates + ((size_t)(b * NH + h) * S_LEN + qrow0 + lane15) * 128 + quad * 8;
#pragma unroll
    for (int c = 0; c < 4; ++c) qfrag[c] = *(const short8*)(qb + c * 32);
  }

  floatx4 o_acc[16];
#pragma unroll
  for (int g = 0; g < 16; ++g) o_acc[g] = (floatx4){0.f, 0.f, 0.f, 0.f};
  float m_i = -1e30f;
  float l_i = 0.f;  // per-lane PARTIAL row-sum; reduced at epilogue

  // ---- hoisted, ch-invariant LDS read offsets (u16 units) ----
  const int kbase = (quad * 16 + lane15) * 8;  // + (t*16+c*4)*128 (imm)
  int vo0[4], vo1[4];
#pragma unroll
  for (int ph = 0; ph < 4; ++ph) {
    int n = ph * 16 + lane15;
    int sw = (n ^ (n >> 3)) & 7;
    vo0[ph] = n * 64 + ((quad ^ sw) & 7) * 8;
    vo1[ph] = n * 64 + (((quad | 4) ^ sw) & 7) * 8;
  }

  // K staging (512 thr, 2 cp16/thread): row = w4*16+lane15, unit u = half*8 + 4j + quad.
  const u16* kp[2];
  int kstr[2];
  int kdst[2];
#pragma unroll
  for (int j = 0; j < 2; ++j) {
    int u = half * 8 + j * 4 + quad;
    const u16* base;
    int str;
    if (u < 8) { base = kv + h * 64 + u * 8; str = 2560; }
    else { base = krope + (u - 8) * 8; str = 64; }
    kp[j] = base + (size_t)(b * S_LEN + w4 * 16 + lane15) * str;
    kstr[j] = str;
    kdst[j] = (w4 * 256 + (half * 2 + j) * 64 + lane) * 8;
  }
  // V staging (512 thr, 4 cp16/thread): n = oi*64 + (tid>>3), slot = tid&7
  const int vn6 = tid >> 3, vsl = tid & 7;
  const u16* vp[4];
#pragma unroll
  for (int oi = 0; oi < 4; ++oi) {
    int n = oi * 64 + vn6;
    int u = vsl ^ ((n ^ (n >> 3)) & 7);
    vp[oi] = vT + ((size_t)pair * 256 + n) * 2048 + u * 8;
  }

  auto issueK = [&](int buf) {
#pragma unroll
    for (int j = 0; j < 2; ++j) {
      cp16(kp[j], &Klds[buf][kdst[j]]);
      kp[j] += (size_t)64 * kstr[j];
    }
  };
  auto issueV = [&](int buf) {
#pragma unroll
    for (int oi = 0; oi < 4; ++oi) {
      cp16(vp[oi], &Vlds[buf][(oi * 512 + tid) * 8]);
      vp[oi] += 64;
    }
  };

  // prologue: fill buf0, drain, converge
  issueK(0);
  issueV(0);
  asm volatile("s_waitcnt vmcnt(0)" ::: "memory");
  __builtin_amdgcn_sched_barrier(0);
  __builtin_amdgcn_s_barrier();

  int cur = 0;
  for (int ch = 0; ch < S_LEN / 64; ++ch) {
    if (ch + 1 < S_LEN / 64) {
      issueK(cur ^ 1);
      issueV(cur ^ 1);
    }

    // S^T = K * Q^T : st[t][r] = S[q=lane15][k = t*16 + quad*4 + r] (log2 domain)
    floatx4 st[4];
#pragma unroll
    for (int t = 0; t < 4; ++t) st[t] = (floatx4){0.f, 0.f, 0.f, 0.f};
    __builtin_amdgcn_s_setprio(1);
#pragma unroll
    for (int c = 0; c < 4; ++c) {
      short8 qf = qfrag[c];
#pragma unroll
      for (int t = 0; t < 4; ++t) {
        short8 kf = *(const short8*)&Klds[cur][kbase + (t * 16 + c * 4) * 128];
        st[t] = mfma16(kf, qf, st[t]);
      }
    }
    __builtin_amdgcn_s_setprio(0);

    // row max: fmax tree + 2-shfl butterfly (l-sum reduce deferred to epilogue)
    float mloc = st[0][0];
#pragma unroll
    for (int t = 0; t < 4; ++t)
#pragma unroll
      for (int r = 0; r < 4; ++r) mloc = fmaxf(mloc, st[t][r]);
    mloc = fmaxf(mloc, __shfl_xor(mloc, 16));
    mloc = fmaxf(mloc, __shfl_xor(mloc, 32));

    // defer-max: only rescale when max grew by >8 (log2 domain); P bounded by 2^8
    const bool resc = __any(mloc > m_i + 8.0f);
    const float mref = resc ? fmaxf(m_i, mloc) : m_i;

    float rs = 0.f;
    union { short8 s; uint4 u; } a01, a23;
    {
      float p0, p1, p2, p3;
      p0 = exp2f(st[0][0] - mref); p1 = exp2f(st[0][1] - mref);
      p2 = exp2f(st[0][2] - mref); p3 = exp2f(st[0][3] - mref);
      rs += (p0 + p1) + (p2 + p3);
      a01.u.x = pkbf(p0, p1); a01.u.y = pkbf(p2, p3);
      p0 = exp2f(st[1][0] - mref); p1 = exp2f(st[1][1] - mref);
      p2 = exp2f(st[1][2] - mref); p3 = exp2f(st[1][3] - mref);
      rs += (p0 + p1) + (p2 + p3);
      a01.u.z = pkbf(p0, p1); a01.u.w = pkbf(p2, p3);
      p0 = exp2f(st[2][0] - mref); p1 = exp2f(st[2][1] - mref);
      p2 = exp2f(st[2][2] - mref); p3 = exp2f(st[2][3] - mref);
      rs += (p0 + p1) + (p2 + p3);
      a23.u.x = pkbf(p0, p1); a23.u.y = pkbf(p2, p3);
      p0 = exp2f(st[3][0] - mref); p1 = exp2f(st[3][1] - mref);
      p2 = exp2f(st[3][2] - mref); p3 = exp2f(st[3][3] - mref);
      rs += (p0 + p1) + (p2 + p3);
      a23.u.z = pkbf(p0, p1); a23.u.w = pkbf(p2, p3);
    }

    if (resc) {  // rare after chunk 0 (THR=8): alpha rescale of o_acc + l_i
      float alpha = exp2f(m_i - mref);
      m_i = mref;
      l_i = l_i * alpha + rs;
      float al[4];
#pragma unroll
      for (int r = 0; r < 4; ++r) al[r] = __shfl(alpha, quad * 4 + r, 16);
#pragma unroll
      for (int g = 0; g < 16; ++g) {
        o_acc[g][0] *= al[0]; o_acc[g][1] *= al[1];
        o_acc[g][2] *= al[2]; o_acc[g][3] *= al[3];
      }
    } else {
      l_i += rs;
    }

    // PV: b-frags are single b128 reads (permuted-k vT layout, hoisted bases)
    __builtin_amdgcn_s_setprio(1);
#pragma unroll
    for (int g = 0; g < 16; ++g) {
      short8 b01 = *(const short8*)&Vlds[cur][vo0[g & 3] + (g >> 2) * 4096];
      short8 b23 = *(const short8*)&Vlds[cur][vo1[g & 3] + (g >> 2) * 4096];
      floatx4 o = o_acc[g];
      o = mfma16(a01.s, b01, o);
      o = mfma16(a23.s, b23, o);
      o_acc[g] = o;
    }
    __builtin_amdgcn_s_setprio(0);

    // single per-chunk sync: next-chunk loads had all of compute to land;
    // barrier seals this chunk's LDS reads before buf[cur] is overwritten.
    asm volatile("s_waitcnt vmcnt(0)" ::: "memory");
    __builtin_amdgcn_sched_barrier(0);
    __builtin_amdgcn_s_barrier();
    cur ^= 1;
  }

  // epilogue: reduce the per-quad partial row-sums once, then normalize
  float lsum = l_i;
  lsum += __shfl_xor(lsum, 16);
  lsum += __shfl_xor(lsum, 32);
  float rl = 1.0f / lsum;
  float linv[4];
#pragma unroll
  for (int r = 0; r < 4; ++r) linv[r] = __shfl(rl, quad * 4 + r, 16);
#pragma unroll
  for (int g = 0; g < 16; ++g) {
#pragma unroll
    for (int r = 0; r < 4; ++r) {
      int row = qrow0 + quad * 4 + r;
      int col = h * 256 + g * 16 + lane15;
      attn_out[((size_t)b * S_LEN + row) * 2048 + col] = f2bf(o_acc[g][r] * linv[r]);
    }
  }
}

extern "C" void kernel_launch(void* const* d_in, const int* in_sizes, int n_in,
                              void* d_out, int out_size, void* d_ws, size_t ws_size,
                              hipStream_t stream) {
  const float* x = (const float*)d_in[0];
  const int* pos = (const int*)d_in[1];
  const float* wdq = (const float*)d_in[2];
  const float* bdq = (const float*)d_in[3];
  const float* qnw = (const float*)d_in[4];
  const float* wuq = (const float*)d_in[5];
  const float* buq = (const float*)d_in[6];
  const float* wdkv = (const float*)d_in[7];
  const float* bdkv = (const float*)d_in[8];
  const float* kvnw = (const float*)d_in[9];
  const float* wukv = (const float*)d_in[10];
  const float* bukv = (const float*)d_in[11];
  const float* wo = (const float*)d_in[12];
  const float* bo = (const float*)d_in[13];
  float* out = (float*)d_out;

  char* ws = (char*)d_ws;
  size_t off = 0;
  auto alloc = [&](size_t bytes) {
    char* p = ws + off;
    off += (bytes + 255) & ~(size_t)255;
    return p;
  };
  // vT (16.78MB) aliases xbf+t0+qout_spacer (22MB): all dead before k_gemm_kv runs.
  // qout is no longer written (stageb fused into k_gemm_q) but KEPT as a spacer so the
  // alias hole stays >= vT size (removing it would shift wKVT into vT's range).
  u16* xbf = (u16*)alloc((size_t)R_TOK * 1024 * 2);    // dead after gemm A
  float* t0 = (float*)alloc((size_t)R_TOK * 320 * 4);  // dead after stagea
  u16* qout = (u16*)alloc((size_t)R_TOK * 1024 * 2);   // UNUSED spacer (alias hole)
  u16* vT = (u16*)d_ws;                                // alias of the three above
  u16* waT = (u16*)alloc((size_t)384 * 1024 * 2);      // padded 320->384 rows
  float* biasA = (float*)alloc(320 * 4);
  u16* wQT = (u16*)alloc((size_t)1024 * 128 * 2);
  u16* wKVT = (u16*)alloc((size_t)2560 * 128 * 2);
  u16* wOT = (u16*)alloc((size_t)1024 * 2048 * 2);
  u16* cq = (u16*)alloc((size_t)R_TOK * 128 * 2);
  u16* ckv = (u16*)alloc((size_t)R_TOK * 128 * 2);
  u16* krope = (u16*)alloc((size_t)R_TOK * 64 * 2);
  u16* qst = (u16*)alloc((size_t)R_TOK * 1024 * 2);
  u16* kvb = (u16*)alloc((size_t)R_TOK * 2560 * 2);
  u16* attnb = (u16*)alloc((size_t)R_TOK * 2048 * 2);
  (void)ws_size; (void)n_in; (void)in_sizes; (void)out_size; (void)qout;

  k_prep<<<6913, 256, 0, stream>>>(x, xbf, wdq, wdkv, waT, wuq, wQT, wukv, wKVT, wo, wOT,
                                   bdq, bdkv, biasA);

  // stage A: x @ [w_dq | w_dkv_kr] -> t0 fp32
  k_gemm_bt<0><<<dim3(3, 32), 256, 0, stream>>>(xbf, waT, biasA, t0, R_TOK, 320, 1024);
  k_stagea<<<R_TOK, 128, 0, stream>>>(t0, qnw, kvnw, pos, cq, ckv, krope);
  // stage B fused: q up-proj + rope + scale + scatter -> qst (no qout round-trip)
  k_gemm_q<<<dim3(8, 32), 256, 0, stream>>>(cq, wQT, buq, pos, qst);
  // kv up-proj fused with V-transpose epilogue: k_nope -> kvb, V -> vT (no k_vt pass)
  k_gemm_kv<<<dim3(20, 32), 256, 0, stream>>>(ckv, wKVT, bukv, kvb, vT);
  // attention: 256 blocks (1/CU, 96KB LDS, 8 waves = 2/SIMD), 512 threads (r3-exact)
  k_attn<<<dim3(16, 16), 512, 0, stream>>>(qst, kvb, krope, vT, attnb);
  // output projection -> fp32 out
  k_gemm_bt<0><<<dim3(8, 32), 256, 0, stream>>>(attnb, wOT, bo, out, R_TOK, 1024, 2048);
}

// Round 7
// 282.122 us; speedup vs baseline: 1.0548x; 1.0078x over previous
//
#include <hip/hip_runtime.h>
#include <hip/hip_bf16.h>
#include <stdint.h>

typedef unsigned short u16;
typedef short short8 __attribute__((ext_vector_type(8)));
typedef float floatx4 __attribute__((ext_vector_type(4)));

#define S_LEN 2048
#define NB 2
#define NH 8
#define R_TOK (NB * S_LEN)  // 4096

#define L2_THETA 13.287712379549449f
// attention scale folded into Q, log2 domain: (1/sqrt(128)) * log2(e)
#define QSCALE (0.08838834764831845f * 1.4426950408889634f)

__device__ inline u16 f2bf(float f) {
  union { float f; uint32_t u; } x; x.f = f;
  uint32_t r = (x.u + 0x7fffu + ((x.u >> 16) & 1u)) >> 16;
  return (u16)r;
}
__device__ inline float bf2f(u16 h) {
  union { uint32_t u; float f; } x; x.u = ((uint32_t)h) << 16;
  return x.f;
}
__device__ inline floatx4 mfma16(short8 a, short8 b, floatx4 c) {
  return __builtin_amdgcn_mfma_f32_16x16x32_bf16(a, b, c, 0, 0, 0);
}
__device__ inline uint32_t pkbf(float a, float b) {
  union { __hip_bfloat162 h; uint32_t u; } c;
  c.h = __float22bfloat162_rn(make_float2(a, b));
  return c.u;
}
__device__ __forceinline__ void cp16(const void* g, const void* l) {
  __builtin_amdgcn_global_load_lds(
      (const __attribute__((address_space(1))) uint32_t*)(uintptr_t)g,
      (__attribute__((address_space(3))) uint32_t*)(uintptr_t)l, 16, 0, 0);
}

// ---------------- fused prep: x->bf16, weight transposes, bias concat ----------------
__global__ __launch_bounds__(256) void k_prep(
    const float* __restrict__ x, u16* __restrict__ xbf,
    const float* __restrict__ wdq, const float* __restrict__ wdkv, u16* __restrict__ waT,
    const float* __restrict__ wuq, u16* __restrict__ wQT,
    const float* __restrict__ wukv, u16* __restrict__ wKVT,
    const float* __restrict__ wo, u16* __restrict__ wOT,
    const float* __restrict__ bdq, const float* __restrict__ bdkv,
    float* __restrict__ biasA) {
  __shared__ u16 tile[32][33];
  const int s = blockIdx.x, tid = threadIdx.x;
  const int tx = tid & 31, ty = tid >> 5;
  if (s < 4096) {
    int i = s * 256 + tid;
    float4 v = ((const float4*)x)[i];
    ushort4 o;
    o.x = f2bf(v.x); o.y = f2bf(v.y); o.z = f2bf(v.z); o.w = f2bf(v.w);
    ((ushort4*)xbf)[i] = o;
  } else if (s < 4416) {  // waT: logical [1024][320] -> [320][1024]
    int t = s - 4096, bx = t % 10, by = t / 10;
    int c0 = bx * 32, r0 = by * 32;
#pragma unroll
    for (int i = 0; i < 4; ++i) {
      int r = r0 + ty + i * 8, c = c0 + tx;
      float v = (c < 128) ? wdq[(size_t)r * 128 + c] : wdkv[(size_t)r * 192 + (c - 128)];
      tile[ty + i * 8][tx] = f2bf(v);
    }
    __syncthreads();
#pragma unroll
    for (int i = 0; i < 4; ++i)
      waT[(size_t)(c0 + ty + i * 8) * 1024 + r0 + tx] = tile[tx][ty + i * 8];
  } else {
    const float* in; u16* out; int R, C, bx, by;
    if (s < 4544) { int t = s - 4416; in = wuq; out = wQT; R = 128; C = 1024; bx = t & 31; by = t >> 5; }
    else if (s < 4864) { int t = s - 4544; in = wukv; out = wKVT; R = 128; C = 2560; bx = t % 80; by = t / 80; }
    else if (s < 6912) { int t = s - 4864; in = wo; out = wOT; R = 2048; C = 1024; bx = t & 31; by = t >> 5; }
    else {
      if (tid < 320) biasA[tid] = (tid < 128) ? bdq[tid] : bdkv[tid - 128];
      return;
    }
    int c0 = bx * 32, r0 = by * 32;
#pragma unroll
    for (int i = 0; i < 4; ++i)
      tile[ty + i * 8][tx] = f2bf(in[(size_t)(r0 + ty + i * 8) * C + c0 + tx]);
    __syncthreads();
#pragma unroll
    for (int i = 0; i < 4; ++i)
      out[(size_t)(c0 + ty + i * 8) * R + r0 + tx] = tile[tx][ty + i * 8];
  }
}

// ---------------- 128x128-tile GEMM, B transposed [N][K], double-buffered async ----------
template <int OUT_BF>
__global__ __launch_bounds__(256) void k_gemm_bt(const u16* __restrict__ A,
                                                 const u16* __restrict__ BT,
                                                 const float* __restrict__ bias,
                                                 void* __restrict__ Cout,
                                                 int M, int N, int K) {
  __shared__ __align__(16) u16 Alds[2][128 * 32];
  __shared__ __align__(16) u16 Blds[2][128 * 32];
  const int tid = threadIdx.x;
  const int wave = tid >> 6, lane = tid & 63;
  const int lane15 = lane & 15, quad = lane >> 4;
  const int m0 = blockIdx.y * 128, n0 = blockIdx.x * 128;
  const int mw = (wave & 1) * 64, nw = (wave >> 1) * 64;

  floatx4 acc[4][4];
#pragma unroll
  for (int a = 0; a < 4; ++a)
#pragma unroll
    for (int b = 0; b < 4; ++b) acc[a][b] = (floatx4){0.f, 0.f, 0.f, 0.f};

  const int srow = wave * 32 + (lane >> 2);
  const int scol = (lane & 3) * 8;

  auto stage = [&](int k0, int buf) {
    const u16* ga = A + (size_t)(m0 + srow) * K + k0 + scol;
    cp16(ga, Alds[buf] + srow * 32 + scol);
    cp16(ga + (size_t)16 * K, Alds[buf] + (srow + 16) * 32 + scol);
    const u16* gb = BT + (size_t)(n0 + srow) * K + k0 + scol;
    cp16(gb, Blds[buf] + srow * 32 + scol);
    cp16(gb + (size_t)16 * K, Blds[buf] + (srow + 16) * 32 + scol);
  };

  stage(0, 0);
  int cur = 0;
  for (int k0 = 0; k0 < K; k0 += 32) {
    __syncthreads();
    if (k0 + 32 < K) stage(k0 + 32, cur ^ 1);
    short8 af[4], bf[4];
#pragma unroll
    for (int im = 0; im < 4; ++im)
      af[im] = *(const short8*)&Alds[cur][(mw + im * 16 + lane15) * 32 + quad * 8];
#pragma unroll
    for (int in = 0; in < 4; ++in)
      bf[in] = *(const short8*)&Blds[cur][(nw + in * 16 + lane15) * 32 + quad * 8];
#pragma unroll
    for (int im = 0; im < 4; ++im)
#pragma unroll
      for (int in = 0; in < 4; ++in) acc[im][in] = mfma16(af[im], bf[in], acc[im][in]);
    cur ^= 1;
  }

#pragma unroll
  for (int im = 0; im < 4; ++im)
#pragma unroll
    for (int in = 0; in < 4; ++in)
#pragma unroll
      for (int r = 0; r < 4; ++r) {
        int row = m0 + mw + im * 16 + quad * 4 + r;
        int col = n0 + nw + in * 16 + lane15;
        if (col < N) {
          float v = acc[im][in][r] + bias[col];
          if (OUT_BF)
            ((u16*)Cout)[(size_t)row * N + col] = f2bf(v);
          else
            ((float*)Cout)[(size_t)row * N + col] = v;
        }
      }
}

// ------- fused Q GEMM (cq @ wQT + buq) + rope + scale + scatter to qstates (r6) -------
// M=4096, N=1024, K=128. Mainloop identical to k_gemm_bt. Epilogue replaces k_stageb:
// saves the 16MB qout round-trip + one launch. Rope pairs (col, col^1) are adjacent
// lanes (lane15^1) -> one __shfl_xor; nope/rope split is block-uniform (n0 >= 768).
__global__ __launch_bounds__(256) void k_gemm_q(const u16* __restrict__ A,
                                                const u16* __restrict__ BT,
                                                const float* __restrict__ bias,
                                                const int* __restrict__ pos_ids,
                                                u16* __restrict__ qstates) {
  const int K = 128;
  __shared__ __align__(16) u16 Alds[2][128 * 32];
  __shared__ __align__(16) u16 Blds[2][128 * 32];
  const int tid = threadIdx.x;
  const int wave = tid >> 6, lane = tid & 63;
  const int lane15 = lane & 15, quad = lane >> 4;
  const int m0 = blockIdx.y * 128, n0 = blockIdx.x * 128;
  const int mw = (wave & 1) * 64, nw = (wave >> 1) * 64;

  floatx4 acc[4][4];
#pragma unroll
  for (int a = 0; a < 4; ++a)
#pragma unroll
    for (int b = 0; b < 4; ++b) acc[a][b] = (floatx4){0.f, 0.f, 0.f, 0.f};

  const int srow = wave * 32 + (lane >> 2);
  const int scol = (lane & 3) * 8;
  auto stage = [&](int k0, int buf) {
    const u16* ga = A + (size_t)(m0 + srow) * K + k0 + scol;
    cp16(ga, Alds[buf] + srow * 32 + scol);
    cp16(ga + (size_t)16 * K, Alds[buf] + (srow + 16) * 32 + scol);
    const u16* gb = BT + (size_t)(n0 + srow) * K + k0 + scol;
    cp16(gb, Blds[buf] + srow * 32 + scol);
    cp16(gb + (size_t)16 * K, Blds[buf] + (srow + 16) * 32 + scol);
  };

  stage(0, 0);
  int cur = 0;
  for (int k0 = 0; k0 < K; k0 += 32) {
    __syncthreads();
    if (k0 + 32 < K) stage(k0 + 32, cur ^ 1);
    short8 af[4], bf[4];
#pragma unroll
    for (int im = 0; im < 4; ++im)
      af[im] = *(const short8*)&Alds[cur][(mw + im * 16 + lane15) * 32 + quad * 8];
#pragma unroll
    for (int in = 0; in < 4; ++in)
      bf[in] = *(const short8*)&Blds[cur][(nw + in * 16 + lane15) * 32 + quad * 8];
#pragma unroll
    for (int im = 0; im < 4; ++im)
#pragma unroll
      for (int in = 0; in < 4; ++in) acc[im][in] = mfma16(af[im], bf[in], acc[im][in]);
    cur ^= 1;
  }

  const bool ropeblk = (n0 >= 768);  // block-uniform: bx>=6
#pragma unroll
  for (int in = 0; in < 4; ++in) {
    const int col = n0 + nw + in * 16 + lane15;
#pragma unroll
    for (int im = 0; im < 4; ++im) {
      if (!ropeblk) {
        const int h = col / 96, d = col - h * 96;
#pragma unroll
        for (int r = 0; r < 4; ++r) {
          int row = m0 + mw + im * 16 + quad * 4 + r;
          int b = row >> 11, s = row & (S_LEN - 1);
          float v = acc[im][in][r] + bias[col];
          qstates[((size_t)(b * NH + h) * S_LEN + s) * 128 + d] = f2bf(v * QSCALE);
        }
      } else {
        const int j = (col - 768) & 31, h = (col - 768) >> 5, pr = j >> 1;
        const float freq = exp2f(-(2.0f * pr / 32.0f) * L2_THETA);
#pragma unroll
        for (int r = 0; r < 4; ++r) {
          int row = m0 + mw + im * 16 + quad * 4 + r;
          int b = row >> 11, s = row & (S_LEN - 1);
          float v = acc[im][in][r] + bias[col];
          float vp = __shfl_xor(v, 1);  // partner col^1 = lane15^1, same row
          float xe = (lane & 1) ? vp : v;
          float xo = (lane & 1) ? v : vp;
          float p = (float)pos_ids[row];
          float ang = p * freq;
          float c = cosf(ang), sn = sinf(ang);
          float val = (j & 1) ? (xe * sn + xo * c) : (xe * c - xo * sn);
          qstates[((size_t)(b * NH + h) * S_LEN + s) * 128 + 96 + j] = f2bf(val * QSCALE);
        }
      }
    }
  }
}

// ------- fused KV GEMM (ckv @ wKVT + bukv) with k_vt folded into the epilogue (r7) -------
// M=4096, N=2560, K=128. cols<512 (k_nope): normal kvb write (stride 2560; V region of
// kvb is never written nor read). cols>=512 (V): r6's direct vT scatter was 8B stores at
// 4KB stride (uncoalesced -> r6 regression). r7: stage the block's 128n x 128p V tile in
// padded LDS (eplds[128][136]: 272B row stride -> 8/16B aligned, <=2-way bank aliasing),
// then cooperative copy-out where 16 consecutive lanes write one 256B-contiguous vT row
// chunk (short8 each) -- same coalescing class as the old k_vt, zero global round-trip.
// Inverse k-permutation identical to r6 (harness-verified): bb=(srow&63)>>2, bits
// b3b2b1b0 -> a = 8*b3+4*b1+2*b0+b2, p_rel = (rrel>>6)*64 + a*4.
__global__ __launch_bounds__(256) void k_gemm_kv(const u16* __restrict__ A,
                                                 const u16* __restrict__ BT,
                                                 const float* __restrict__ bias,
                                                 u16* __restrict__ kvb,
                                                 u16* __restrict__ vT) {
  const int K = 128, N = 2560;
  __shared__ __align__(16) u16 Alds[2][128 * 32];
  __shared__ __align__(16) u16 Blds[2][128 * 32];
  __shared__ __align__(16) u16 eplds[128 * 136];  // V epilogue staging, 34.8 KB
  const int tid = threadIdx.x;
  const int wave = tid >> 6, lane = tid & 63;
  const int lane15 = lane & 15, quad = lane >> 4;
  const int m0 = blockIdx.y * 128, n0 = blockIdx.x * 128;
  const int mw = (wave & 1) * 64, nw = (wave >> 1) * 64;

  floatx4 acc[4][4];
#pragma unroll
  for (int a = 0; a < 4; ++a)
#pragma unroll
    for (int b = 0; b < 4; ++b) acc[a][b] = (floatx4){0.f, 0.f, 0.f, 0.f};

  const int srow = wave * 32 + (lane >> 2);
  const int scol = (lane & 3) * 8;
  auto stage = [&](int k0, int buf) {
    const u16* ga = A + (size_t)(m0 + srow) * K + k0 + scol;
    cp16(ga, Alds[buf] + srow * 32 + scol);
    cp16(ga + (size_t)16 * K, Alds[buf] + (srow + 16) * 32 + scol);
    const u16* gb = BT + (size_t)(n0 + srow) * K + k0 + scol;
    cp16(gb, Blds[buf] + srow * 32 + scol);
    cp16(gb + (size_t)16 * K, Blds[buf] + (srow + 16) * 32 + scol);
  };

  stage(0, 0);
  int cur = 0;
  for (int k0 = 0; k0 < K; k0 += 32) {
    __syncthreads();
    if (k0 + 32 < K) stage(k0 + 32, cur ^ 1);
    short8 af[4], bf[4];
#pragma unroll
    for (int im = 0; im < 4; ++im)
      af[im] = *(const short8*)&Alds[cur][(mw + im * 16 + lane15) * 32 + quad * 8];
#pragma unroll
    for (int in = 0; in < 4; ++in)
      bf[in] = *(const short8*)&Blds[cur][(nw + in * 16 + lane15) * 32 + quad * 8];
#pragma unroll
    for (int im = 0; im < 4; ++im)
#pragma unroll
      for (int in = 0; in < 4; ++in) acc[im][in] = mfma16(af[im], bf[in], acc[im][in]);
    cur ^= 1;
  }

  if (n0 < 512) {  // k_nope region: block-uniform (bx<4)
#pragma unroll
    for (int im = 0; im < 4; ++im)
#pragma unroll
      for (int in = 0; in < 4; ++in)
#pragma unroll
        for (int r = 0; r < 4; ++r) {
          int row = m0 + mw + im * 16 + quad * 4 + r;
          int col = n0 + nw + in * 16 + lane15;
          kvb[(size_t)row * N + col] = f2bf(acc[im][in][r] + bias[col]);
        }
  } else {  // V region -> eplds (permuted-k layout) -> coalesced vT copy-out
#pragma unroll
    for (int im = 0; im < 4; ++im) {
      const int rrel = mw + im * 16 + quad * 4;  // block-relative s, 0..127
      const int bb = (rrel & 63) >> 2;
      const int a = (bb & 8) | (((bb >> 1) & 1) << 2) | ((bb & 1) << 1) | ((bb >> 2) & 1);
      const int prel = (rrel >> 6) * 64 + a * 4;
#pragma unroll
      for (int in = 0; in < 4; ++in) {
        const int nl = nw + in * 16 + lane15;
        const float bv = bias[n0 + nl];
        ushort4 o;
        o.x = f2bf(acc[im][in][0] + bv);
        o.y = f2bf(acc[im][in][1] + bv);
        o.z = f2bf(acc[im][in][2] + bv);
        o.w = f2bf(acc[im][in][3] + bv);
        *(ushort4*)&eplds[nl * 136 + prel] = o;
      }
    }
    __syncthreads();
    const int sbase = m0 & (S_LEN - 1), bq = m0 >> 11;  // block rows all in one batch
#pragma unroll
    for (int i = 0; i < 8; ++i) {
      int idx = i * 256 + tid;
      int nl = idx >> 4, c8 = (idx & 15) * 8;
      int c2 = n0 + nl - 512;
      int hv = c2 >> 8, nn = c2 & 255;
      short8 v = *(const short8*)&eplds[nl * 136 + c8];
      *(short8*)&vT[((size_t)((bq * NH + hv) * 256 + nn)) * 2048 + sbase + c8] = v;
    }
  }
}

// ---------------- stage-A epilogue: rmsnorm(cq), rmsnorm(ckv), rope(k_rope) ----------------
__global__ void k_stagea(const float* __restrict__ t0, const float* __restrict__ qnw,
                         const float* __restrict__ kvnw, const int* __restrict__ pos_ids,
                         u16* __restrict__ cq, u16* __restrict__ ckv,
                         u16* __restrict__ krope) {
  int r = blockIdx.x, tid = threadIdx.x;  // 128 threads
  const float* row = t0 + (size_t)r * 320;
  float a = row[tid];
  float b = row[128 + tid];
  float sa = a * a, sb = b * b;
#pragma unroll
  for (int d = 1; d < 64; d <<= 1) {
    sa += __shfl_xor(sa, d);
    sb += __shfl_xor(sb, d);
  }
  __shared__ float red[4];
  if ((tid & 63) == 0) { red[(tid >> 6) * 2] = sa; red[(tid >> 6) * 2 + 1] = sb; }
  __syncthreads();
  sa = red[0] + red[2];
  sb = red[1] + red[3];
  float ra = rsqrtf(sa * (1.0f / 128.0f) + 1e-8f);
  float rb = rsqrtf(sb * (1.0f / 128.0f) + 1e-8f);
  cq[(size_t)r * 128 + tid] = f2bf(qnw[tid] * a * ra);
  ckv[(size_t)r * 128 + tid] = f2bf(kvnw[tid] * b * rb);
  if (tid < 32) {
    float xe = row[256 + 2 * tid], xo = row[256 + 2 * tid + 1];
    float p = (float)pos_ids[r];
    float freq = exp2f(-(2.0f * tid / 64.0f) * L2_THETA);
    float ang = p * freq;
    float c = cosf(ang), s = sinf(ang);
    krope[(size_t)r * 64 + 2 * tid] = f2bf(xe * c - xo * s);
    krope[(size_t)r * 64 + 2 * tid + 1] = f2bf(xe * s + xo * c);
  }
}

// ---------------- flash attention: 2-phase double-buffered pipeline (r3-exact) ----------
// Best-known attn (89-90us). r5's n-split (LDS-read reduction) regressed +26%: the kernel
// is NOT LDS-BW-bound; duplicated QK MFMA + 2x softmax VALU dominated. Keep r3 structure.
__global__ __launch_bounds__(512) void k_attn(const u16* __restrict__ qstates,
                                              const u16* __restrict__ kv,
                                              const u16* __restrict__ krope,
                                              const u16* __restrict__ vT,
                                              u16* __restrict__ attn_out) {
  const int pair = blockIdx.x;  // 0..15 (pair-major: XCD = pair%8)
  const int qblk = blockIdx.y;  // 0..15
  const int b = pair >> 3, h = pair & 7;
  const int tid = threadIdx.x;
  const int wave = tid >> 6, lane = tid & 63;
  const int lane15 = lane & 15, quad = lane >> 4;
  const int w4 = wave & 3, half = wave >> 2;

  __shared__ __align__(16) u16 Klds[2][64 * 128];   // 2 x 16 KB
  __shared__ __align__(16) u16 Vlds[2][256 * 64];   // 2 x 32 KB

  const int qrow0 = qblk * 128 + wave * 16;
  short8 qfrag[4];
  {
    const u16* qb = qstates + ((size_t)(b * NH + h) * S_LEN + qrow0 + lane15) * 128 + quad * 8;
#pragma unroll
    for (int c = 0; c < 4; ++c) qfrag[c] = *(const short8*)(qb + c * 32);
  }

  floatx4 o_acc[16];
#pragma unroll
  for (int g = 0; g < 16; ++g) o_acc[g] = (floatx4){0.f, 0.f, 0.f, 0.f};
  float m_i = -1e30f;
  float l_i = 0.f;  // per-lane PARTIAL row-sum; reduced at epilogue

  // ---- hoisted, ch-invariant LDS read offsets (u16 units) ----
  const int kbase = (quad * 16 + lane15) * 8;  // + (t*16+c*4)*128 (imm)
  int vo0[4], vo1[4];
#pragma unroll
  for (int ph = 0; ph < 4; ++ph) {
    int n = ph * 16 + lane15;
    int sw = (n ^ (n >> 3)) & 7;
    vo0[ph] = n * 64 + ((quad ^ sw) & 7) * 8;
    vo1[ph] = n * 64 + (((quad | 4) ^ sw) & 7) * 8;
  }

  // K staging (512 thr, 2 cp16/thread): row = w4*16+lane15, unit u = half*8 + 4j + quad.
  const u16* kp[2];
  int kstr[2];
  int kdst[2];
#pragma unroll
  for (int j = 0; j < 2; ++j) {
    int u = half * 8 + j * 4 + quad;
    const u16* base;
    int str;
    if (u < 8) { base = kv + h * 64 + u * 8; str = 2560; }
    else { base = krope + (u - 8) * 8; str = 64; }
    kp[j] = base + (size_t)(b * S_LEN + w4 * 16 + lane15) * str;
    kstr[j] = str;
    kdst[j] = (w4 * 256 + (half * 2 + j) * 64 + lane) * 8;
  }
  // V staging (512 thr, 4 cp16/thread): n = oi*64 + (tid>>3), slot = tid&7
  const int vn6 = tid >> 3, vsl = tid & 7;
  const u16* vp[4];
#pragma unroll
  for (int oi = 0; oi < 4; ++oi) {
    int n = oi * 64 + vn6;
    int u = vsl ^ ((n ^ (n >> 3)) & 7);
    vp[oi] = vT + ((size_t)pair * 256 + n) * 2048 + u * 8;
  }

  auto issueK = [&](int buf) {
#pragma unroll
    for (int j = 0; j < 2; ++j) {
      cp16(kp[j], &Klds[buf][kdst[j]]);
      kp[j] += (size_t)64 * kstr[j];
    }
  };
  auto issueV = [&](int buf) {
#pragma unroll
    for (int oi = 0; oi < 4; ++oi) {
      cp16(vp[oi], &Vlds[buf][(oi * 512 + tid) * 8]);
      vp[oi] += 64;
    }
  };

  // prologue: fill buf0, drain, converge
  issueK(0);
  issueV(0);
  asm volatile("s_waitcnt vmcnt(0)" ::: "memory");
  __builtin_amdgcn_sched_barrier(0);
  __builtin_amdgcn_s_barrier();

  int cur = 0;
  for (int ch = 0; ch < S_LEN / 64; ++ch) {
    if (ch + 1 < S_LEN / 64) {
      issueK(cur ^ 1);
      issueV(cur ^ 1);
    }

    // S^T = K * Q^T : st[t][r] = S[q=lane15][k = t*16 + quad*4 + r] (log2 domain)
    floatx4 st[4];
#pragma unroll
    for (int t = 0; t < 4; ++t) st[t] = (floatx4){0.f, 0.f, 0.f, 0.f};
    __builtin_amdgcn_s_setprio(1);
#pragma unroll
    for (int c = 0; c < 4; ++c) {
      short8 qf = qfrag[c];
#pragma unroll
      for (int t = 0; t < 4; ++t) {
        short8 kf = *(const short8*)&Klds[cur][kbase + (t * 16 + c * 4) * 128];
        st[t] = mfma16(kf, qf, st[t]);
      }
    }
    __builtin_amdgcn_s_setprio(0);

    // row max: fmax tree + 2-shfl butterfly (l-sum reduce deferred to epilogue)
    float mloc = st[0][0];
#pragma unroll
    for (int t = 0; t < 4; ++t)
#pragma unroll
      for (int r = 0; r < 4; ++r) mloc = fmaxf(mloc, st[t][r]);
    mloc = fmaxf(mloc, __shfl_xor(mloc, 16));
    mloc = fmaxf(mloc, __shfl_xor(mloc, 32));

    // defer-max: only rescale when max grew by >8 (log2 domain); P bounded by 2^8
    const bool resc = __any(mloc > m_i + 8.0f);
    const float mref = resc ? fmaxf(m_i, mloc) : m_i;

    float rs = 0.f;
    union { short8 s; uint4 u; } a01, a23;
    {
      float p0, p1, p2, p3;
      p0 = exp2f(st[0][0] - mref); p1 = exp2f(st[0][1] - mref);
      p2 = exp2f(st[0][2] - mref); p3 = exp2f(st[0][3] - mref);
      rs += (p0 + p1) + (p2 + p3);
      a01.u.x = pkbf(p0, p1); a01.u.y = pkbf(p2, p3);
      p0 = exp2f(st[1][0] - mref); p1 = exp2f(st[1][1] - mref);
      p2 = exp2f(st[1][2] - mref); p3 = exp2f(st[1][3] - mref);
      rs += (p0 + p1) + (p2 + p3);
      a01.u.z = pkbf(p0, p1); a01.u.w = pkbf(p2, p3);
      p0 = exp2f(st[2][0] - mref); p1 = exp2f(st[2][1] - mref);
      p2 = exp2f(st[2][2] - mref); p3 = exp2f(st[2][3] - mref);
      rs += (p0 + p1) + (p2 + p3);
      a23.u.x = pkbf(p0, p1); a23.u.y = pkbf(p2, p3);
      p0 = exp2f(st[3][0] - mref); p1 = exp2f(st[3][1] - mref);
      p2 = exp2f(st[3][2] - mref); p3 = exp2f(st[3][3] - mref);
      rs += (p0 + p1) + (p2 + p3);
      a23.u.z = pkbf(p0, p1); a23.u.w = pkbf(p2, p3);
    }

    if (resc) {  // rare after chunk 0 (THR=8): alpha rescale of o_acc + l_i
      float alpha = exp2f(m_i - mref);
      m_i = mref;
      l_i = l_i * alpha + rs;
      float al[4];
#pragma unroll
      for (int r = 0; r < 4; ++r) al[r] = __shfl(alpha, quad * 4 + r, 16);
#pragma unroll
      for (int g = 0; g < 16; ++g) {
        o_acc[g][0] *= al[0]; o_acc[g][1] *= al[1];
        o_acc[g][2] *= al[2]; o_acc[g][3] *= al[3];
      }
    } else {
      l_i += rs;
    }

    // PV: b-frags are single b128 reads (permuted-k vT layout, hoisted bases)
    __builtin_amdgcn_s_setprio(1);
#pragma unroll
    for (int g = 0; g < 16; ++g) {
      short8 b01 = *(const short8*)&Vlds[cur][vo0[g & 3] + (g >> 2) * 4096];
      short8 b23 = *(const short8*)&Vlds[cur][vo1[g & 3] + (g >> 2) * 4096];
      floatx4 o = o_acc[g];
      o = mfma16(a01.s, b01, o);
      o = mfma16(a23.s, b23, o);
      o_acc[g] = o;
    }
    __builtin_amdgcn_s_setprio(0);

    // single per-chunk sync: next-chunk loads had all of compute to land;
    // barrier seals this chunk's LDS reads before buf[cur] is overwritten.
    asm volatile("s_waitcnt vmcnt(0)" ::: "memory");
    __builtin_amdgcn_sched_barrier(0);
    __builtin_amdgcn_s_barrier();
    cur ^= 1;
  }

  // epilogue: reduce the per-quad partial row-sums once, then normalize
  float lsum = l_i;
  lsum += __shfl_xor(lsum, 16);
  lsum += __shfl_xor(lsum, 32);
  float rl = 1.0f / lsum;
  float linv[4];
#pragma unroll
  for (int r = 0; r < 4; ++r) linv[r] = __shfl(rl, quad * 4 + r, 16);
#pragma unroll
  for (int g = 0; g < 16; ++g) {
#pragma unroll
    for (int r = 0; r < 4; ++r) {
      int row = qrow0 + quad * 4 + r;
      int col = h * 256 + g * 16 + lane15;
      attn_out[((size_t)b * S_LEN + row) * 2048 + col] = f2bf(o_acc[g][r] * linv[r]);
    }
  }
}

extern "C" void kernel_launch(void* const* d_in, const int* in_sizes, int n_in,
                              void* d_out, int out_size, void* d_ws, size_t ws_size,
                              hipStream_t stream) {
  const float* x = (const float*)d_in[0];
  const int* pos = (const int*)d_in[1];
  const float* wdq = (const float*)d_in[2];
  const float* bdq = (const float*)d_in[3];
  const float* qnw = (const float*)d_in[4];
  const float* wuq = (const float*)d_in[5];
  const float* buq = (const float*)d_in[6];
  const float* wdkv = (const float*)d_in[7];
  const float* bdkv = (const float*)d_in[8];
  const float* kvnw = (const float*)d_in[9];
  const float* wukv = (const float*)d_in[10];
  const float* bukv = (const float*)d_in[11];
  const float* wo = (const float*)d_in[12];
  const float* bo = (const float*)d_in[13];
  float* out = (float*)d_out;

  char* ws = (char*)d_ws;
  size_t off = 0;
  auto alloc = [&](size_t bytes) {
    char* p = ws + off;
    off += (bytes + 255) & ~(size_t)255;
    return p;
  };
  // vT (16.78MB) aliases xbf+t0+qout_spacer (22MB): all dead before k_gemm_kv runs.
  // qout is no longer written (stageb fused into k_gemm_q) but KEPT as a spacer so the
  // alias hole stays >= vT size (removing it would shift wKVT into vT's range).
  u16* xbf = (u16*)alloc((size_t)R_TOK * 1024 * 2);    // dead after gemm A
  float* t0 = (float*)alloc((size_t)R_TOK * 320 * 4);  // dead after stagea
  u16* qout = (u16*)alloc((size_t)R_TOK * 1024 * 2);   // UNUSED spacer (alias hole)
  u16* vT = (u16*)d_ws;                                // alias of the three above
  u16* waT = (u16*)alloc((size_t)384 * 1024 * 2);      // padded 320->384 rows
  float* biasA = (float*)alloc(320 * 4);
  u16* wQT = (u16*)alloc((size_t)1024 * 128 * 2);
  u16* wKVT = (u16*)alloc((size_t)2560 * 128 * 2);
  u16* wOT = (u16*)alloc((size_t)1024 * 2048 * 2);
  u16* cq = (u16*)alloc((size_t)R_TOK * 128 * 2);
  u16* ckv = (u16*)alloc((size_t)R_TOK * 128 * 2);
  u16* krope = (u16*)alloc((size_t)R_TOK * 64 * 2);
  u16* qst = (u16*)alloc((size_t)R_TOK * 1024 * 2);
  u16* kvb = (u16*)alloc((size_t)R_TOK * 2560 * 2);
  u16* attnb = (u16*)alloc((size_t)R_TOK * 2048 * 2);
  (void)ws_size; (void)n_in; (void)in_sizes; (void)out_size; (void)qout;

  k_prep<<<6913, 256, 0, stream>>>(x, xbf, wdq, wdkv, waT, wuq, wQT, wukv, wKVT, wo, wOT,
                                   bdq, bdkv, biasA);

  // stage A: x @ [w_dq | w_dkv_kr] -> t0 fp32
  k_gemm_bt<0><<<dim3(3, 32), 256, 0, stream>>>(xbf, waT, biasA, t0, R_TOK, 320, 1024);
  k_stagea<<<R_TOK, 128, 0, stream>>>(t0, qnw, kvnw, pos, cq, ckv, krope);
  // stage B fused: q up-proj + rope + scale + scatter -> qst (no qout round-trip)
  k_gemm_q<<<dim3(8, 32), 256, 0, stream>>>(cq, wQT, buq, pos, qst);
  // kv up-proj fused with V-transpose epilogue (LDS-staged coalesced vT writes)
  k_gemm_kv<<<dim3(20, 32), 256, 0, stream>>>(ckv, wKVT, bukv, kvb, vT);
  // attention: 256 blocks (1/CU, 96KB LDS, 8 waves = 2/SIMD), 512 threads (r3-exact)
  k_attn<<<dim3(16, 16), 512, 0, stream>>>(qst, kvb, krope, vT, attnb);
  // output projection -> fp32 out
  k_gemm_bt<0><<<dim3(8, 32), 256, 0, stream>>>(attnb, wOT, bo, out, R_TOK, 1024, 2048);
}

// Round 8
// 258.979 us; speedup vs baseline: 1.1491x; 1.0894x over previous
//
#include <hip/hip_runtime.h>
#include <hip/hip_bf16.h>
#include <stdint.h>

typedef unsigned short u16;
typedef short short8 __attribute__((ext_vector_type(8)));
typedef float floatx4 __attribute__((ext_vector_type(4)));

#define S_LEN 2048
#define NB 2
#define NH 8
#define R_TOK (NB * S_LEN)  // 4096

#define L2_THETA 13.287712379549449f
// attention scale folded into Q, log2 domain: (1/sqrt(128)) * log2(e)
#define QSCALE (0.08838834764831845f * 1.4426950408889634f)

__device__ inline u16 f2bf(float f) {
  union { float f; uint32_t u; } x; x.f = f;
  uint32_t r = (x.u + 0x7fffu + ((x.u >> 16) & 1u)) >> 16;
  return (u16)r;
}
__device__ inline float bf2f(u16 h) {
  union { uint32_t u; float f; } x; x.u = ((uint32_t)h) << 16;
  return x.f;
}
__device__ inline floatx4 mfma16(short8 a, short8 b, floatx4 c) {
  return __builtin_amdgcn_mfma_f32_16x16x32_bf16(a, b, c, 0, 0, 0);
}
__device__ inline uint32_t pkbf(float a, float b) {
  union { __hip_bfloat162 h; uint32_t u; } c;
  c.h = __float22bfloat162_rn(make_float2(a, b));
  return c.u;
}
__device__ __forceinline__ void cp16(const void* g, const void* l) {
  __builtin_amdgcn_global_load_lds(
      (const __attribute__((address_space(1))) uint32_t*)(uintptr_t)g,
      (__attribute__((address_space(3))) uint32_t*)(uintptr_t)l, 16, 0, 0);
}

// ---------------- fused prep: x->bf16, weight transposes, bias concat ----------------
__global__ __launch_bounds__(256) void k_prep(
    const float* __restrict__ x, u16* __restrict__ xbf,
    const float* __restrict__ wdq, const float* __restrict__ wdkv, u16* __restrict__ waT,
    const float* __restrict__ wuq, u16* __restrict__ wQT,
    const float* __restrict__ wukv, u16* __restrict__ wKVT,
    const float* __restrict__ wo, u16* __restrict__ wOT,
    const float* __restrict__ bdq, const float* __restrict__ bdkv,
    float* __restrict__ biasA) {
  __shared__ u16 tile[32][33];
  const int s = blockIdx.x, tid = threadIdx.x;
  const int tx = tid & 31, ty = tid >> 5;
  if (s < 4096) {
    int i = s * 256 + tid;
    float4 v = ((const float4*)x)[i];
    ushort4 o;
    o.x = f2bf(v.x); o.y = f2bf(v.y); o.z = f2bf(v.z); o.w = f2bf(v.w);
    ((ushort4*)xbf)[i] = o;
  } else if (s < 4416) {  // waT: logical [1024][320] -> [320][1024]
    int t = s - 4096, bx = t % 10, by = t / 10;
    int c0 = bx * 32, r0 = by * 32;
#pragma unroll
    for (int i = 0; i < 4; ++i) {
      int r = r0 + ty + i * 8, c = c0 + tx;
      float v = (c < 128) ? wdq[(size_t)r * 128 + c] : wdkv[(size_t)r * 192 + (c - 128)];
      tile[ty + i * 8][tx] = f2bf(v);
    }
    __syncthreads();
#pragma unroll
    for (int i = 0; i < 4; ++i)
      waT[(size_t)(c0 + ty + i * 8) * 1024 + r0 + tx] = tile[tx][ty + i * 8];
  } else {
    const float* in; u16* out; int R, C, bx, by;
    if (s < 4544) { int t = s - 4416; in = wuq; out = wQT; R = 128; C = 1024; bx = t & 31; by = t >> 5; }
    else if (s < 4864) { int t = s - 4544; in = wukv; out = wKVT; R = 128; C = 2560; bx = t % 80; by = t / 80; }
    else if (s < 6912) { int t = s - 4864; in = wo; out = wOT; R = 2048; C = 1024; bx = t & 31; by = t >> 5; }
    else {
      if (tid < 320) biasA[tid] = (tid < 128) ? bdq[tid] : bdkv[tid - 128];
      return;
    }
    int c0 = bx * 32, r0 = by * 32;
#pragma unroll
    for (int i = 0; i < 4; ++i)
      tile[ty + i * 8][tx] = f2bf(in[(size_t)(r0 + ty + i * 8) * C + c0 + tx]);
    __syncthreads();
#pragma unroll
    for (int i = 0; i < 4; ++i)
      out[(size_t)(c0 + ty + i * 8) * R + r0 + tx] = tile[tx][ty + i * 8];
  }
}

// ---------------- 128x128-tile GEMM, B transposed [N][K], double-buffered async ----------
template <int OUT_BF>
__global__ __launch_bounds__(256) void k_gemm_bt(const u16* __restrict__ A,
                                                 const u16* __restrict__ BT,
                                                 const float* __restrict__ bias,
                                                 void* __restrict__ Cout,
                                                 int M, int N, int K) {
  __shared__ __align__(16) u16 Alds[2][128 * 32];
  __shared__ __align__(16) u16 Blds[2][128 * 32];
  const int tid = threadIdx.x;
  const int wave = tid >> 6, lane = tid & 63;
  const int lane15 = lane & 15, quad = lane >> 4;
  const int m0 = blockIdx.y * 128, n0 = blockIdx.x * 128;
  const int mw = (wave & 1) * 64, nw = (wave >> 1) * 64;

  floatx4 acc[4][4];
#pragma unroll
  for (int a = 0; a < 4; ++a)
#pragma unroll
    for (int b = 0; b < 4; ++b) acc[a][b] = (floatx4){0.f, 0.f, 0.f, 0.f};

  const int srow = wave * 32 + (lane >> 2);
  const int scol = (lane & 3) * 8;

  auto stage = [&](int k0, int buf) {
    const u16* ga = A + (size_t)(m0 + srow) * K + k0 + scol;
    cp16(ga, Alds[buf] + srow * 32 + scol);
    cp16(ga + (size_t)16 * K, Alds[buf] + (srow + 16) * 32 + scol);
    const u16* gb = BT + (size_t)(n0 + srow) * K + k0 + scol;
    cp16(gb, Blds[buf] + srow * 32 + scol);
    cp16(gb + (size_t)16 * K, Blds[buf] + (srow + 16) * 32 + scol);
  };

  stage(0, 0);
  int cur = 0;
  for (int k0 = 0; k0 < K; k0 += 32) {
    __syncthreads();
    if (k0 + 32 < K) stage(k0 + 32, cur ^ 1);
    short8 af[4], bf[4];
#pragma unroll
    for (int im = 0; im < 4; ++im)
      af[im] = *(const short8*)&Alds[cur][(mw + im * 16 + lane15) * 32 + quad * 8];
#pragma unroll
    for (int in = 0; in < 4; ++in)
      bf[in] = *(const short8*)&Blds[cur][(nw + in * 16 + lane15) * 32 + quad * 8];
#pragma unroll
    for (int im = 0; im < 4; ++im)
#pragma unroll
      for (int in = 0; in < 4; ++in) acc[im][in] = mfma16(af[im], bf[in], acc[im][in]);
    cur ^= 1;
  }

#pragma unroll
  for (int im = 0; im < 4; ++im)
#pragma unroll
    for (int in = 0; in < 4; ++in)
#pragma unroll
      for (int r = 0; r < 4; ++r) {
        int row = m0 + mw + im * 16 + quad * 4 + r;
        int col = n0 + nw + in * 16 + lane15;
        if (col < N) {
          float v = acc[im][in][r] + bias[col];
          if (OUT_BF)
            ((u16*)Cout)[(size_t)row * N + col] = f2bf(v);
          else
            ((float*)Cout)[(size_t)row * N + col] = v;
        }
      }
}

// ------- fused Q GEMM (cq @ wQT + buq) + rope + scale + scatter to qstates (r8) -------
// M=4096, N=1024, K=128. Epilogue replaces k_stageb (saves 16MB qout round-trip).
// r8: (A) grid transposed to dim3(32,8) (m-tile on x) so rope blocks (y in {6,7}) spread
// across all 8 XCDs instead of piling on XCDs 6/7 (r6/r7 straggler tail). (B) cos/sin
// from precomputed qtab (written by k_stagea, bitwise-identical formula) -> no
// transcendentals in the epilogue at all.
__global__ __launch_bounds__(256) void k_gemm_q(const u16* __restrict__ A,
                                                const u16* __restrict__ BT,
                                                const float* __restrict__ bias,
                                                const float* __restrict__ qtab,
                                                u16* __restrict__ qstates) {
  const int K = 128;
  __shared__ __align__(16) u16 Alds[2][128 * 32];
  __shared__ __align__(16) u16 Blds[2][128 * 32];
  const int tid = threadIdx.x;
  const int wave = tid >> 6, lane = tid & 63;
  const int lane15 = lane & 15, quad = lane >> 4;
  const int m0 = blockIdx.x * 128, n0 = blockIdx.y * 128;  // transposed grid (fix A)
  const int mw = (wave & 1) * 64, nw = (wave >> 1) * 64;

  floatx4 acc[4][4];
#pragma unroll
  for (int a = 0; a < 4; ++a)
#pragma unroll
    for (int b = 0; b < 4; ++b) acc[a][b] = (floatx4){0.f, 0.f, 0.f, 0.f};

  const int srow = wave * 32 + (lane >> 2);
  const int scol = (lane & 3) * 8;
  auto stage = [&](int k0, int buf) {
    const u16* ga = A + (size_t)(m0 + srow) * K + k0 + scol;
    cp16(ga, Alds[buf] + srow * 32 + scol);
    cp16(ga + (size_t)16 * K, Alds[buf] + (srow + 16) * 32 + scol);
    const u16* gb = BT + (size_t)(n0 + srow) * K + k0 + scol;
    cp16(gb, Blds[buf] + srow * 32 + scol);
    cp16(gb + (size_t)16 * K, Blds[buf] + (srow + 16) * 32 + scol);
  };

  stage(0, 0);
  int cur = 0;
  for (int k0 = 0; k0 < K; k0 += 32) {
    __syncthreads();
    if (k0 + 32 < K) stage(k0 + 32, cur ^ 1);
    short8 af[4], bf[4];
#pragma unroll
    for (int im = 0; im < 4; ++im)
      af[im] = *(const short8*)&Alds[cur][(mw + im * 16 + lane15) * 32 + quad * 8];
#pragma unroll
    for (int in = 0; in < 4; ++in)
      bf[in] = *(const short8*)&Blds[cur][(nw + in * 16 + lane15) * 32 + quad * 8];
#pragma unroll
    for (int im = 0; im < 4; ++im)
#pragma unroll
      for (int in = 0; in < 4; ++in) acc[im][in] = mfma16(af[im], bf[in], acc[im][in]);
    cur ^= 1;
  }

  const bool ropeblk = (n0 >= 768);  // block-uniform: y>=6
#pragma unroll
  for (int in = 0; in < 4; ++in) {
    const int col = n0 + nw + in * 16 + lane15;
#pragma unroll
    for (int im = 0; im < 4; ++im) {
      if (!ropeblk) {
        const int h = col / 96, d = col - h * 96;
#pragma unroll
        for (int r = 0; r < 4; ++r) {
          int row = m0 + mw + im * 16 + quad * 4 + r;
          int b = row >> 11, s = row & (S_LEN - 1);
          float v = acc[im][in][r] + bias[col];
          qstates[((size_t)(b * NH + h) * S_LEN + s) * 128 + d] = f2bf(v * QSCALE);
        }
      } else {
        const int j = (col - 768) & 31, h = (col - 768) >> 5, pr = j >> 1;
#pragma unroll
        for (int r = 0; r < 4; ++r) {
          int row = m0 + mw + im * 16 + quad * 4 + r;
          int b = row >> 11, s = row & (S_LEN - 1);
          float v = acc[im][in][r] + bias[col];
          float vp = __shfl_xor(v, 1);  // partner col^1 = lane15^1, same row
          float xe = (lane & 1) ? vp : v;
          float xo = (lane & 1) ? v : vp;
          float2 cs = *(const float2*)&qtab[((size_t)row * 16 + pr) * 2];  // (cos, sin)
          float val = (j & 1) ? (xe * cs.y + xo * cs.x) : (xe * cs.x - xo * cs.y);
          qstates[((size_t)(b * NH + h) * S_LEN + s) * 128 + 96 + j] = f2bf(val * QSCALE);
        }
      }
    }
  }
}

// ------- fused KV GEMM (ckv @ wKVT + bukv) with k_vt folded into the epilogue (r8) -------
// M=4096, N=2560, K=128. cols<512 (k_nope): normal kvb write. cols>=512 (V): LDS-staged
// coalesced vT write (r7), but eplds halved to [64][136] (17.4KB; total LDS 49.4KB ->
// 3 blocks/CU, fixing r7's 2/CU occupancy tail). Two passes over in-halves:
// slot = (nl&31) | ((nl&64)>>1); inverse nl = (slot&31) + hh*32 + ((slot&32)<<1).
// Permutation math identical to r6/r7 (harness-verified).
__global__ __launch_bounds__(256) void k_gemm_kv(const u16* __restrict__ A,
                                                 const u16* __restrict__ BT,
                                                 const float* __restrict__ bias,
                                                 u16* __restrict__ kvb,
                                                 u16* __restrict__ vT) {
  const int K = 128, N = 2560;
  __shared__ __align__(16) u16 Alds[2][128 * 32];
  __shared__ __align__(16) u16 Blds[2][128 * 32];
  __shared__ __align__(16) u16 eplds[64 * 136];  // V epilogue staging, 17.4 KB
  const int tid = threadIdx.x;
  const int wave = tid >> 6, lane = tid & 63;
  const int lane15 = lane & 15, quad = lane >> 4;
  const int m0 = blockIdx.y * 128, n0 = blockIdx.x * 128;
  const int mw = (wave & 1) * 64, nw = (wave >> 1) * 64;

  floatx4 acc[4][4];
#pragma unroll
  for (int a = 0; a < 4; ++a)
#pragma unroll
    for (int b = 0; b < 4; ++b) acc[a][b] = (floatx4){0.f, 0.f, 0.f, 0.f};

  const int srow = wave * 32 + (lane >> 2);
  const int scol = (lane & 3) * 8;
  auto stage = [&](int k0, int buf) {
    const u16* ga = A + (size_t)(m0 + srow) * K + k0 + scol;
    cp16(ga, Alds[buf] + srow * 32 + scol);
    cp16(ga + (size_t)16 * K, Alds[buf] + (srow + 16) * 32 + scol);
    const u16* gb = BT + (size_t)(n0 + srow) * K + k0 + scol;
    cp16(gb, Blds[buf] + srow * 32 + scol);
    cp16(gb + (size_t)16 * K, Blds[buf] + (srow + 16) * 32 + scol);
  };

  stage(0, 0);
  int cur = 0;
  for (int k0 = 0; k0 < K; k0 += 32) {
    __syncthreads();
    if (k0 + 32 < K) stage(k0 + 32, cur ^ 1);
    short8 af[4], bf[4];
#pragma unroll
    for (int im = 0; im < 4; ++im)
      af[im] = *(const short8*)&Alds[cur][(mw + im * 16 + lane15) * 32 + quad * 8];
#pragma unroll
    for (int in = 0; in < 4; ++in)
      bf[in] = *(const short8*)&Blds[cur][(nw + in * 16 + lane15) * 32 + quad * 8];
#pragma unroll
    for (int im = 0; im < 4; ++im)
#pragma unroll
      for (int in = 0; in < 4; ++in) acc[im][in] = mfma16(af[im], bf[in], acc[im][in]);
    cur ^= 1;
  }

  if (n0 < 512) {  // k_nope region: block-uniform (bx<4)
#pragma unroll
    for (int im = 0; im < 4; ++im)
#pragma unroll
      for (int in = 0; in < 4; ++in)
#pragma unroll
        for (int r = 0; r < 4; ++r) {
          int row = m0 + mw + im * 16 + quad * 4 + r;
          int col = n0 + nw + in * 16 + lane15;
          kvb[(size_t)row * N + col] = f2bf(acc[im][in][r] + bias[col]);
        }
  } else {  // V region: two-pass LDS-staged coalesced vT write
    const int sbase = m0 & (S_LEN - 1), bq = m0 >> 11;
#pragma unroll
    for (int hh = 0; hh < 2; ++hh) {
#pragma unroll
      for (int im = 0; im < 4; ++im) {
        const int rrel = mw + im * 16 + quad * 4;  // block-relative s, 0..127
        const int bb = (rrel & 63) >> 2;
        const int a = (bb & 8) | (((bb >> 1) & 1) << 2) | ((bb & 1) << 1) | ((bb >> 2) & 1);
        const int prel = (rrel >> 6) * 64 + a * 4;
#pragma unroll
        for (int ii = 0; ii < 2; ++ii) {
          const int in = hh * 2 + ii;
          const int nl = nw + in * 16 + lane15;
          const int slot = (nl & 31) | ((nl & 64) >> 1);
          const float bv = bias[n0 + nl];
          ushort4 o;
          o.x = f2bf(acc[im][in][0] + bv);
          o.y = f2bf(acc[im][in][1] + bv);
          o.z = f2bf(acc[im][in][2] + bv);
          o.w = f2bf(acc[im][in][3] + bv);
          *(ushort4*)&eplds[slot * 136 + prel] = o;
        }
      }
      __syncthreads();
#pragma unroll
      for (int i = 0; i < 4; ++i) {
        int idx = i * 256 + tid;
        int slot = idx >> 4, c8 = (idx & 15) * 8;
        int nl = (slot & 31) + hh * 32 + ((slot & 32) << 1);
        int c2 = n0 + nl - 512;
        int hv = c2 >> 8, nn = c2 & 255;
        short8 v = *(const short8*)&eplds[slot * 136 + c8];
        *(short8*)&vT[((size_t)((bq * NH + hv) * 256 + nn)) * 2048 + sbase + c8] = v;
      }
      if (hh == 0) __syncthreads();
    }
  }
}

// ------- stage-A epilogue: rmsnorm(cq), rmsnorm(ckv), rope(k_rope), q-rope table -------
__global__ void k_stagea(const float* __restrict__ t0, const float* __restrict__ qnw,
                         const float* __restrict__ kvnw, const int* __restrict__ pos_ids,
                         u16* __restrict__ cq, u16* __restrict__ ckv,
                         u16* __restrict__ krope, float* __restrict__ qtab) {
  int r = blockIdx.x, tid = threadIdx.x;  // 128 threads
  const float* row = t0 + (size_t)r * 320;
  float a = row[tid];
  float b = row[128 + tid];
  float sa = a * a, sb = b * b;
#pragma unroll
  for (int d = 1; d < 64; d <<= 1) {
    sa += __shfl_xor(sa, d);
    sb += __shfl_xor(sb, d);
  }
  __shared__ float red[4];
  if ((tid & 63) == 0) { red[(tid >> 6) * 2] = sa; red[(tid >> 6) * 2 + 1] = sb; }
  __syncthreads();
  sa = red[0] + red[2];
  sb = red[1] + red[3];
  float ra = rsqrtf(sa * (1.0f / 128.0f) + 1e-8f);
  float rb = rsqrtf(sb * (1.0f / 128.0f) + 1e-8f);
  cq[(size_t)r * 128 + tid] = f2bf(qnw[tid] * a * ra);
  ckv[(size_t)r * 128 + tid] = f2bf(kvnw[tid] * b * rb);
  if (tid < 32) {
    float xe = row[256 + 2 * tid], xo = row[256 + 2 * tid + 1];
    float p = (float)pos_ids[r];
    float freq = exp2f(-(2.0f * tid / 64.0f) * L2_THETA);
    float ang = p * freq;
    float c = cosf(ang), s = sinf(ang);
    krope[(size_t)r * 64 + 2 * tid] = f2bf(xe * c - xo * s);
    krope[(size_t)r * 64 + 2 * tid + 1] = f2bf(xe * s + xo * c);
  } else if (tid < 48) {
    // q-rope table: bitwise-identical formula to the old k_stageb path
    int pr = tid - 32;
    float p = (float)pos_ids[r];
    float freq = exp2f(-(2.0f * pr / 32.0f) * L2_THETA);
    float ang = p * freq;
    qtab[((size_t)r * 16 + pr) * 2] = cosf(ang);
    qtab[((size_t)r * 16 + pr) * 2 + 1] = sinf(ang);
  }
}

// ---------------- flash attention: 2-phase double-buffered pipeline (r3-exact) ----------
// Best-known attn (88.8-90us). r5's n-split regressed +26% (duplicated QK MFMA + 2x
// softmax VALU dominate any LDS-read saving). Keep r3 structure untouched.
__global__ __launch_bounds__(512) void k_attn(const u16* __restrict__ qstates,
                                              const u16* __restrict__ kv,
                                              const u16* __restrict__ krope,
                                              const u16* __restrict__ vT,
                                              u16* __restrict__ attn_out) {
  const int pair = blockIdx.x;  // 0..15 (pair-major: XCD = pair%8)
  const int qblk = blockIdx.y;  // 0..15
  const int b = pair >> 3, h = pair & 7;
  const int tid = threadIdx.x;
  const int wave = tid >> 6, lane = tid & 63;
  const int lane15 = lane & 15, quad = lane >> 4;
  const int w4 = wave & 3, half = wave >> 2;

  __shared__ __align__(16) u16 Klds[2][64 * 128];   // 2 x 16 KB
  __shared__ __align__(16) u16 Vlds[2][256 * 64];   // 2 x 32 KB

  const int qrow0 = qblk * 128 + wave * 16;
  short8 qfrag[4];
  {
    const u16* qb = qstates + ((size_t)(b * NH + h) * S_LEN + qrow0 + lane15) * 128 + quad * 8;
#pragma unroll
    for (int c = 0; c < 4; ++c) qfrag[c] = *(const short8*)(qb + c * 32);
  }

  floatx4 o_acc[16];
#pragma unroll
  for (int g = 0; g < 16; ++g) o_acc[g] = (floatx4){0.f, 0.f, 0.f, 0.f};
  float m_i = -1e30f;
  float l_i = 0.f;  // per-lane PARTIAL row-sum; reduced at epilogue

  // ---- hoisted, ch-invariant LDS read offsets (u16 units) ----
  const int kbase = (quad * 16 + lane15) * 8;  // + (t*16+c*4)*128 (imm)
  int vo0[4], vo1[4];
#pragma unroll
  for (int ph = 0; ph < 4; ++ph) {
    int n = ph * 16 + lane15;
    int sw = (n ^ (n >> 3)) & 7;
    vo0[ph] = n * 64 + ((quad ^ sw) & 7) * 8;
    vo1[ph] = n * 64 + (((quad | 4) ^ sw) & 7) * 8;
  }

  // K staging (512 thr, 2 cp16/thread): row = w4*16+lane15, unit u = half*8 + 4j + quad.
  const u16* kp[2];
  int kstr[2];
  int kdst[2];
#pragma unroll
  for (int j = 0; j < 2; ++j) {
    int u = half * 8 + j * 4 + quad;
    const u16* base;
    int str;
    if (u < 8) { base = kv + h * 64 + u * 8; str = 2560; }
    else { base = krope + (u - 8) * 8; str = 64; }
    kp[j] = base + (size_t)(b * S_LEN + w4 * 16 + lane15) * str;
    kstr[j] = str;
    kdst[j] = (w4 * 256 + (half * 2 + j) * 64 + lane) * 8;
  }
  // V staging (512 thr, 4 cp16/thread): n = oi*64 + (tid>>3), slot = tid&7
  const int vn6 = tid >> 3, vsl = tid & 7;
  const u16* vp[4];
#pragma unroll
  for (int oi = 0; oi < 4; ++oi) {
    int n = oi * 64 + vn6;
    int u = vsl ^ ((n ^ (n >> 3)) & 7);
    vp[oi] = vT + ((size_t)pair * 256 + n) * 2048 + u * 8;
  }

  auto issueK = [&](int buf) {
#pragma unroll
    for (int j = 0; j < 2; ++j) {
      cp16(kp[j], &Klds[buf][kdst[j]]);
      kp[j] += (size_t)64 * kstr[j];
    }
  };
  auto issueV = [&](int buf) {
#pragma unroll
    for (int oi = 0; oi < 4; ++oi) {
      cp16(vp[oi], &Vlds[buf][(oi * 512 + tid) * 8]);
      vp[oi] += 64;
    }
  };

  // prologue: fill buf0, drain, converge
  issueK(0);
  issueV(0);
  asm volatile("s_waitcnt vmcnt(0)" ::: "memory");
  __builtin_amdgcn_sched_barrier(0);
  __builtin_amdgcn_s_barrier();

  int cur = 0;
  for (int ch = 0; ch < S_LEN / 64; ++ch) {
    if (ch + 1 < S_LEN / 64) {
      issueK(cur ^ 1);
      issueV(cur ^ 1);
    }

    // S^T = K * Q^T : st[t][r] = S[q=lane15][k = t*16 + quad*4 + r] (log2 domain)
    floatx4 st[4];
#pragma unroll
    for (int t = 0; t < 4; ++t) st[t] = (floatx4){0.f, 0.f, 0.f, 0.f};
    __builtin_amdgcn_s_setprio(1);
#pragma unroll
    for (int c = 0; c < 4; ++c) {
      short8 qf = qfrag[c];
#pragma unroll
      for (int t = 0; t < 4; ++t) {
        short8 kf = *(const short8*)&Klds[cur][kbase + (t * 16 + c * 4) * 128];
        st[t] = mfma16(kf, qf, st[t]);
      }
    }
    __builtin_amdgcn_s_setprio(0);

    // row max: fmax tree + 2-shfl butterfly (l-sum reduce deferred to epilogue)
    float mloc = st[0][0];
#pragma unroll
    for (int t = 0; t < 4; ++t)
#pragma unroll
      for (int r = 0; r < 4; ++r) mloc = fmaxf(mloc, st[t][r]);
    mloc = fmaxf(mloc, __shfl_xor(mloc, 16));
    mloc = fmaxf(mloc, __shfl_xor(mloc, 32));

    // defer-max: only rescale when max grew by >8 (log2 domain); P bounded by 2^8
    const bool resc = __any(mloc > m_i + 8.0f);
    const float mref = resc ? fmaxf(m_i, mloc) : m_i;

    float rs = 0.f;
    union { short8 s; uint4 u; } a01, a23;
    {
      float p0, p1, p2, p3;
      p0 = exp2f(st[0][0] - mref); p1 = exp2f(st[0][1] - mref);
      p2 = exp2f(st[0][2] - mref); p3 = exp2f(st[0][3] - mref);
      rs += (p0 + p1) + (p2 + p3);
      a01.u.x = pkbf(p0, p1); a01.u.y = pkbf(p2, p3);
      p0 = exp2f(st[1][0] - mref); p1 = exp2f(st[1][1] - mref);
      p2 = exp2f(st[1][2] - mref); p3 = exp2f(st[1][3] - mref);
      rs += (p0 + p1) + (p2 + p3);
      a01.u.z = pkbf(p0, p1); a01.u.w = pkbf(p2, p3);
      p0 = exp2f(st[2][0] - mref); p1 = exp2f(st[2][1] - mref);
      p2 = exp2f(st[2][2] - mref); p3 = exp2f(st[2][3] - mref);
      rs += (p0 + p1) + (p2 + p3);
      a23.u.x = pkbf(p0, p1); a23.u.y = pkbf(p2, p3);
      p0 = exp2f(st[3][0] - mref); p1 = exp2f(st[3][1] - mref);
      p2 = exp2f(st[3][2] - mref); p3 = exp2f(st[3][3] - mref);
      rs += (p0 + p1) + (p2 + p3);
      a23.u.z = pkbf(p0, p1); a23.u.w = pkbf(p2, p3);
    }

    if (resc) {  // rare after chunk 0 (THR=8): alpha rescale of o_acc + l_i
      float alpha = exp2f(m_i - mref);
      m_i = mref;
      l_i = l_i * alpha + rs;
      float al[4];
#pragma unroll
      for (int r = 0; r < 4; ++r) al[r] = __shfl(alpha, quad * 4 + r, 16);
#pragma unroll
      for (int g = 0; g < 16; ++g) {
        o_acc[g][0] *= al[0]; o_acc[g][1] *= al[1];
        o_acc[g][2] *= al[2]; o_acc[g][3] *= al[3];
      }
    } else {
      l_i += rs;
    }

    // PV: b-frags are single b128 reads (permuted-k vT layout, hoisted bases)
    __builtin_amdgcn_s_setprio(1);
#pragma unroll
    for (int g = 0; g < 16; ++g) {
      short8 b01 = *(const short8*)&Vlds[cur][vo0[g & 3] + (g >> 2) * 4096];
      short8 b23 = *(const short8*)&Vlds[cur][vo1[g & 3] + (g >> 2) * 4096];
      floatx4 o = o_acc[g];
      o = mfma16(a01.s, b01, o);
      o = mfma16(a23.s, b23, o);
      o_acc[g] = o;
    }
    __builtin_amdgcn_s_setprio(0);

    // single per-chunk sync: next-chunk loads had all of compute to land;
    // barrier seals this chunk's LDS reads before buf[cur] is overwritten.
    asm volatile("s_waitcnt vmcnt(0)" ::: "memory");
    __builtin_amdgcn_sched_barrier(0);
    __builtin_amdgcn_s_barrier();
    cur ^= 1;
  }

  // epilogue: reduce the per-quad partial row-sums once, then normalize
  float lsum = l_i;
  lsum += __shfl_xor(lsum, 16);
  lsum += __shfl_xor(lsum, 32);
  float rl = 1.0f / lsum;
  float linv[4];
#pragma unroll
  for (int r = 0; r < 4; ++r) linv[r] = __shfl(rl, quad * 4 + r, 16);
#pragma unroll
  for (int g = 0; g < 16; ++g) {
#pragma unroll
    for (int r = 0; r < 4; ++r) {
      int row = qrow0 + quad * 4 + r;
      int col = h * 256 + g * 16 + lane15;
      attn_out[((size_t)b * S_LEN + row) * 2048 + col] = f2bf(o_acc[g][r] * linv[r]);
    }
  }
}

extern "C" void kernel_launch(void* const* d_in, const int* in_sizes, int n_in,
                              void* d_out, int out_size, void* d_ws, size_t ws_size,
                              hipStream_t stream) {
  const float* x = (const float*)d_in[0];
  const int* pos = (const int*)d_in[1];
  const float* wdq = (const float*)d_in[2];
  const float* bdq = (const float*)d_in[3];
  const float* qnw = (const float*)d_in[4];
  const float* wuq = (const float*)d_in[5];
  const float* buq = (const float*)d_in[6];
  const float* wdkv = (const float*)d_in[7];
  const float* bdkv = (const float*)d_in[8];
  const float* kvnw = (const float*)d_in[9];
  const float* wukv = (const float*)d_in[10];
  const float* bukv = (const float*)d_in[11];
  const float* wo = (const float*)d_in[12];
  const float* bo = (const float*)d_in[13];
  float* out = (float*)d_out;

  char* ws = (char*)d_ws;
  size_t off = 0;
  auto alloc = [&](size_t bytes) {
    char* p = ws + off;
    off += (bytes + 255) & ~(size_t)255;
    return p;
  };
  // vT (16.78MB) aliases xbf+t0+qout_spacer (22MB): all dead before k_gemm_kv runs.
  // qout is no longer written (stageb fused into k_gemm_q) but KEPT as a spacer so the
  // alias hole stays >= vT size (removing it would shift wKVT into vT's range).
  u16* xbf = (u16*)alloc((size_t)R_TOK * 1024 * 2);    // dead after gemm A
  float* t0 = (float*)alloc((size_t)R_TOK * 320 * 4);  // dead after stagea
  u16* qout = (u16*)alloc((size_t)R_TOK * 1024 * 2);   // UNUSED spacer (alias hole)
  u16* vT = (u16*)d_ws;                                // alias of the three above
  u16* waT = (u16*)alloc((size_t)384 * 1024 * 2);      // padded 320->384 rows
  float* biasA = (float*)alloc(320 * 4);
  u16* wQT = (u16*)alloc((size_t)1024 * 128 * 2);
  u16* wKVT = (u16*)alloc((size_t)2560 * 128 * 2);
  u16* wOT = (u16*)alloc((size_t)1024 * 2048 * 2);
  u16* cq = (u16*)alloc((size_t)R_TOK * 128 * 2);
  u16* ckv = (u16*)alloc((size_t)R_TOK * 128 * 2);
  u16* krope = (u16*)alloc((size_t)R_TOK * 64 * 2);
  u16* qst = (u16*)alloc((size_t)R_TOK * 1024 * 2);
  u16* kvb = (u16*)alloc((size_t)R_TOK * 2560 * 2);
  u16* attnb = (u16*)alloc((size_t)R_TOK * 2048 * 2);
  float* qtab = (float*)alloc((size_t)R_TOK * 16 * 2 * 4);  // q-rope cos/sin table, 512KB
  (void)ws_size; (void)n_in; (void)in_sizes; (void)out_size; (void)qout;

  k_prep<<<6913, 256, 0, stream>>>(x, xbf, wdq, wdkv, waT, wuq, wQT, wukv, wKVT, wo, wOT,
                                   bdq, bdkv, biasA);

  // stage A: x @ [w_dq | w_dkv_kr] -> t0 fp32
  k_gemm_bt<0><<<dim3(3, 32), 256, 0, stream>>>(xbf, waT, biasA, t0, R_TOK, 320, 1024);
  k_stagea<<<R_TOK, 128, 0, stream>>>(t0, qnw, kvnw, pos, cq, ckv, krope, qtab);
  // stage B fused: q up-proj + rope(table) + scale + scatter -> qst; transposed grid
  // spreads rope blocks (y in {6,7}) across all XCDs
  k_gemm_q<<<dim3(32, 8), 256, 0, stream>>>(cq, wQT, buq, qtab, qst);
  // kv up-proj fused with V-transpose epilogue (two-pass LDS staging, 3 blocks/CU)
  k_gemm_kv<<<dim3(20, 32), 256, 0, stream>>>(ckv, wKVT, bukv, kvb, vT);
  // attention: 256 blocks (1/CU, 96KB LDS, 8 waves = 2/SIMD), 512 threads (r3-exact)
  k_attn<<<dim3(16, 16), 512, 0, stream>>>(qst, kvb, krope, vT, attnb);
  // output projection -> fp32 out
  k_gemm_bt<0><<<dim3(8, 32), 256, 0, stream>>>(attnb, wOT, bo, out, R_TOK, 1024, 2048);
}